// Round 7
// baseline (2722.840 us; speedup 1.0000x reference)
//
#include <hip/hip_runtime.h>
#include <math.h>

#define NS 4
#define NB 32
#define CIN 128
#define NCOUT 256
#define HWN 256
#define ND 1152
#define NK 8192   // NB*HWN
static const size_t D2 = (size_t)ND * ND;

typedef __attribute__((ext_vector_type(8))) short bf16x8;
typedef __attribute__((ext_vector_type(4))) float f32x4;

static __device__ inline unsigned short f2bf(float x) {
  unsigned int u = __float_as_uint(x);
  unsigned int r = (u + 0x7fffu + ((u >> 16) & 1u)) >> 16;
  return (unsigned short)r;
}
static __device__ inline float bf2f(unsigned short h) {
  return __uint_as_float(((unsigned int)h) << 16);
}

// ---------------- small prep kernels ----------------

__global__ void k_sqrtp(const float* __restrict__ lp, float* __restrict__ sp,
                        float* __restrict__ pp) {
  int b = threadIdx.x;
  if (b < NB) sp[b] = expf(0.5f * lp[b]);
  if (b < 8) pp[b] = 0.f;
}

__global__ __launch_bounds__(128) void k_patches(const float* __restrict__ X,
                                                 const float* __restrict__ sp,
                                                 unsigned short* __restrict__ Phi,
                                                 unsigned short* __restrict__ Plo) {
  int d = blockIdx.x, s = blockIdx.y, t = threadIdx.x;
  int c = d / 9, r = d % 9, ky = r / 3, kx = r % 3;
  int p0 = t * 2;
  int yy = (p0 >> 4) + ky - 1;
  int xx0 = (p0 & 15) + kx - 1;
  bool oky = (yy >= 0 && yy < 16);
  bool ok0 = oky && (xx0 >= 0) && (xx0 < 16);
  bool ok1 = oky && (xx0 + 1 >= 0) && (xx0 + 1 < 16);
  int xo = yy * 16 + xx0;
  size_t base = ((size_t)s * ND + d) * NK + p0;
  for (int b = 0; b < NB; ++b) {
    float sb = sp[b];
    const float* xb = X + ((size_t)(s * NB + b) * CIN + c) * HWN;
    float v0 = ok0 ? xb[xo] * sb : 0.f;
    float v1 = ok1 ? xb[xo + 1] * sb : 0.f;
    unsigned short h0 = f2bf(v0), h1 = f2bf(v1);
    unsigned short l0 = f2bf(v0 - bf2f(h0)), l1 = f2bf(v1 - bf2f(h1));
    size_t idx = base + (size_t)b * HWN;
    *(unsigned int*)(Phi + idx) = (unsigned int)h0 | ((unsigned int)h1 << 16);
    *(unsigned int*)(Plo + idx) = (unsigned int)l0 | ((unsigned int)l1 << 16);
  }
}

__global__ __launch_bounds__(128) void k_ytt(const float* __restrict__ u,
                                             const float* __restrict__ sp,
                                             unsigned short* __restrict__ Yhi,
                                             unsigned short* __restrict__ Ylo) {
  int c = blockIdx.x, t = threadIdx.x;
  int p0 = t * 2;
  for (int b = 0; b < NB; ++b) {
    float sb = sp[b];
    const float* ub = u + ((size_t)b * NCOUT + c) * HWN + p0;
    float v0 = ub[0] * sb, v1 = ub[1] * sb;
    unsigned short h0 = f2bf(v0), h1 = f2bf(v1);
    unsigned short l0 = f2bf(v0 - bf2f(h0)), l1 = f2bf(v1 - bf2f(h1));
    size_t idx = (size_t)c * NK + (size_t)b * HWN + p0;
    *(unsigned int*)(Yhi + idx) = (unsigned int)h0 | ((unsigned int)h1 << 16);
    *(unsigned int*)(Ylo + idx) = (unsigned int)l0 | ((unsigned int)l1 << 16);
  }
}

// ---------------- bf16x3 MFMA XLX/XLY, K-split by 2 (partial sums) ----------------
__global__ __launch_bounds__(256) void k_gemm_mfma(
    const unsigned short* __restrict__ Phi, const unsigned short* __restrict__ Plo,
    const unsigned short* __restrict__ Yhi, const unsigned short* __restrict__ Ylo,
    float* __restrict__ prec, float* __restrict__ prec2,
    float* __restrict__ XLY, float* __restrict__ XLY2) {
  int jt = blockIdx.x, it = blockIdx.y;
  int s = blockIdx.z >> 1, kp = blockIdx.z & 1;
  bool isX = (jt <= it);
  if (!isX && jt < 9) return;
  int i0 = it * 128;
  int j0;
  const unsigned short *Bh, *Bl;
  if (isX) {
    j0 = jt * 128;
    Bh = Phi + ((size_t)s * ND + j0) * NK;
    Bl = Plo + ((size_t)s * ND + j0) * NK;
  } else {
    j0 = (jt - 9) * 128;
    Bh = Yhi + (size_t)j0 * NK;
    Bl = Ylo + (size_t)j0 * NK;
  }
  const unsigned short* Ah = Phi + ((size_t)s * ND + i0) * NK;
  const unsigned short* Al = Plo + ((size_t)s * ND + i0) * NK;

  __shared__ unsigned short sAh[4096], sAl[4096], sBh[4096], sBl[4096];
  int tid = threadIdx.x, wave = tid >> 6, lane = tid & 63;
  int wr = wave >> 1, wc = wave & 1;

  f32x4 zero = {0.f, 0.f, 0.f, 0.f};
  f32x4 acc[4][4];
#pragma unroll
  for (int m = 0; m < 4; ++m)
#pragma unroll
    for (int n = 0; n < 4; ++n) acc[m][n] = zero;

  const unsigned short* srcs[4] = {Ah, Al, Bh, Bl};
  unsigned short* dsts[4] = {sAh, sAl, sBh, sBl};
  int r0l = lane >> 2;
  int ke = (lane & 3) * 8;
  int arow0 = wr * 64 + (lane & 15);
  int brow0 = wc * 64 + (lane & 15);
  int koff = (lane >> 4) * 8;

  int kbeg = kp * (NK / 2), kend = kbeg + NK / 2;
  for (int k0 = kbeg; k0 < kend; k0 += 32) {
    __syncthreads();
#pragma unroll
    for (int f = 0; f < 4; ++f) {
#pragma unroll
      for (int cc = 0; cc < 2; ++cc) {
        int c = wave * 2 + cc;
        const unsigned short* g = srcs[f] + (size_t)(c * 16 + r0l) * NK + k0 + ke;
        unsigned short* l = dsts[f] + c * 512;
        __builtin_amdgcn_global_load_lds(
            (const __attribute__((address_space(1))) void*)g,
            (__attribute__((address_space(3))) void*)l, 16, 0, 0);
      }
    }
    __syncthreads();
    bf16x8 ah[4], al[4], bh[4], bl[4];
#pragma unroll
    for (int m = 0; m < 4; ++m) {
      int off = (arow0 + m * 16) * 32 + koff;
      ah[m] = *(const bf16x8*)&sAh[off];
      al[m] = *(const bf16x8*)&sAl[off];
    }
#pragma unroll
    for (int n = 0; n < 4; ++n) {
      int off = (brow0 + n * 16) * 32 + koff;
      bh[n] = *(const bf16x8*)&sBh[off];
      bl[n] = *(const bf16x8*)&sBl[off];
    }
#pragma unroll
    for (int m = 0; m < 4; ++m)
#pragma unroll
      for (int n = 0; n < 4; ++n) {
        acc[m][n] = __builtin_amdgcn_mfma_f32_16x16x32_bf16(ah[m], bh[n], acc[m][n], 0, 0, 0);
        acc[m][n] = __builtin_amdgcn_mfma_f32_16x16x32_bf16(ah[m], bl[n], acc[m][n], 0, 0, 0);
        acc[m][n] = __builtin_amdgcn_mfma_f32_16x16x32_bf16(al[m], bh[n], acc[m][n], 0, 0, 0);
      }
  }

  if (isX) {
    float* base = (kp ? prec2 : prec) + (size_t)s * D2;
#pragma unroll
    for (int m = 0; m < 4; ++m) {
      int row = i0 + wr * 64 + m * 16 + (lane >> 4) * 4;
#pragma unroll
      for (int n = 0; n < 4; ++n) {
        int col = j0 + wc * 64 + n * 16 + (lane & 15);
        float* cp = base + (size_t)row * ND + col;
#pragma unroll
        for (int r = 0; r < 4; ++r) cp[(size_t)r * ND] = acc[m][n][r];
      }
    }
  } else {
    float* base = (kp ? XLY2 : XLY) + (size_t)s * ND * NCOUT;
#pragma unroll
    for (int m = 0; m < 4; ++m) {
      int row = i0 + wr * 64 + m * 16 + (lane >> 4) * 4;
#pragma unroll
      for (int n = 0; n < 4; ++n) {
        int col = j0 + wc * 64 + n * 16 + (lane & 15);
        float* cp = base + (size_t)row * NCOUT + col;
#pragma unroll
        for (int r = 0; r < 4; ++r) cp[(size_t)r * NCOUT] = acc[m][n][r];
      }
    }
  }
}

// ================= single DAG mega-kernel: Cholesky + fwd solve + bwd solve =================
// 1-D grid, 315 blocks/sample: [0,171) chol tiles (t0 ascending), [171,243) fwd (r asc x ct),
// [243,315) bwd (r desc x ct). All deps have strictly smaller block index within a sample.
// Flags per sample (468): [0,324) chol i*18+j; [324,396) fwd r*4+ct; [396,468) bwd r*4+ct.
__global__ __launch_bounds__(256) void k_dag(
    float* __restrict__ L, const float* __restrict__ Lp2,
    const float* __restrict__ B1, const float* __restrict__ B2,
    const float* __restrict__ Z, float* __restrict__ iA64,
    float* __restrict__ logd, float* __restrict__ Xf, float* __restrict__ Xb,
    float* __restrict__ Wm, float* __restrict__ pp, int* __restrict__ flags) {
  int s = blockIdx.x / 315;
  int t = blockIdx.x % 315;
  float* Ls = L + (size_t)s * D2;
  int* fc = flags + s * 468;
  int tid = threadIdx.x, tx = tid & 15, ty = tid >> 4;
  int lane = tid & 63, w = tid >> 6;

  __shared__ float At[64][68];
  __shared__ float Bt[64][68];
  __shared__ float red[8];

#define WAITF(idx)                                                             \
  do {                                                                         \
    if (tid == 0) {                                                            \
      while (__hip_atomic_load(&fc[idx], __ATOMIC_RELAXED,                     \
                               __HIP_MEMORY_SCOPE_AGENT) == 0)                 \
        __builtin_amdgcn_s_sleep(2);                                           \
      (void)__hip_atomic_load(&fc[idx], __ATOMIC_ACQUIRE,                      \
                              __HIP_MEMORY_SCOPE_AGENT);                       \
    }                                                                          \
  } while (0)
#define RELF(idx)                                                              \
  do {                                                                         \
    if (tid == 0)                                                              \
      __hip_atomic_store(&fc[idx], 1, __ATOMIC_RELEASE,                        \
                         __HIP_MEMORY_SCOPE_AGENT);                            \
  } while (0)

  if (t < 171) {
    // ---------------- Cholesky tile ----------------
    int bi = 0;
    while ((bi + 1) * (bi + 2) / 2 <= t) ++bi;
    int bj = t - bi * (bi + 1) / 2;
    int ib = bi * 64, jb = bj * 64;
    const float* Ps = Lp2 + (size_t)s * D2;

    float acc[4][4];
#pragma unroll
    for (int r = 0; r < 4; ++r) {
      size_t idx = (size_t)(ib + ty * 4 + r) * ND + jb + tx * 4;
      float4 v = *(const float4*)(Ls + idx);
      float4 v2 = *(const float4*)(Ps + idx);
      acc[r][0] = v.x + v2.x; acc[r][1] = v.y + v2.y;
      acc[r][2] = v.z + v2.z; acc[r][3] = v.w + v2.w;
    }
    if (bi == bj) {
#pragma unroll
      for (int r = 0; r < 4; ++r)
#pragma unroll
        for (int e = 0; e < 4; ++e)
          if (ty * 4 + r == tx * 4 + e) acc[r][e] += 1.f;
    }

    for (int k = 0; k < bj; ++k) {
      WAITF(bi * 18 + k);
      WAITF(bj * 18 + k);
      __syncthreads();
      int kb = k * 64;
      {
        int a2 = tid >> 2, km = (tid & 3) * 4;
#pragma unroll
        for (int m = 0; m < 4; ++m) {
          float4 v = *(const float4*)(Ls + (size_t)(ib + a2) * ND + kb + km + m * 16);
          At[km + m * 16 + 0][a2] = v.x;
          At[km + m * 16 + 1][a2] = v.y;
          At[km + m * 16 + 2][a2] = v.z;
          At[km + m * 16 + 3][a2] = v.w;
          float4 u4 = *(const float4*)(Ls + (size_t)(jb + a2) * ND + kb + km + m * 16);
          Bt[km + m * 16 + 0][a2] = u4.x;
          Bt[km + m * 16 + 1][a2] = u4.y;
          Bt[km + m * 16 + 2][a2] = u4.z;
          Bt[km + m * 16 + 3][a2] = u4.w;
        }
      }
      __syncthreads();
#pragma unroll
      for (int kc = 0; kc < 64; ++kc) {
        float4 a4 = *(const float4*)&At[kc][ty * 4];
        float4 b4 = *(const float4*)&Bt[kc][tx * 4];
        float ar[4] = {a4.x, a4.y, a4.z, a4.w};
        float br[4] = {b4.x, b4.y, b4.z, b4.w};
#pragma unroll
        for (int r = 0; r < 4; ++r)
#pragma unroll
          for (int e = 0; e < 4; ++e) acc[r][e] = fmaf(-ar[r], br[e], acc[r][e]);
      }
      __syncthreads();
    }

    if (bi == bj) {
      // diag: fused factor + inverse (single wave)
#pragma unroll
      for (int r = 0; r < 4; ++r)
#pragma unroll
        for (int e = 0; e < 4; ++e) At[ty * 4 + r][tx * 4 + e] = acc[r][e];
      __syncthreads();
      if (w == 0) {
        float a[64], x[64];
#pragma unroll
        for (int tt = 0; tt < 64; ++tt) {
          a[tt] = At[lane][tt];
          x[tt] = (tt == lane) ? 1.f : 0.f;
        }
        float diagv = 1.f;
#pragma unroll
        for (int j = 0; j < 64; ++j) {
          float dj = __shfl(a[j], j, 64);
          float rinv = 1.0f / sqrtf(dj);
          a[j] *= rinv;
          x[j] *= rinv;
          if (lane == j) diagv = a[j];
#pragma unroll
          for (int tt = j + 1; tt < 64; ++tt) {
            float ltj = __shfl(a[j], tt, 64);
            a[tt] = fmaf(-a[j], ltj, a[tt]);
            x[tt] = fmaf(-x[j], ltj, x[tt]);
          }
        }
#pragma unroll
        for (int tt = 0; tt < 64; ++tt) At[lane][tt] = (tt <= lane) ? a[tt] : 0.f;
#pragma unroll
        for (int i = 0; i < 64; ++i) Bt[i][lane] = x[i];  // iA[i][lane]
        logd[s * ND + ib + lane] = logf(diagv);
      }
      __syncthreads();
      {
        float* q = iA64 + (size_t)(s * 18 + bi) * 4096;
        int rr = tid >> 2, c4 = (tid & 3) * 16;
#pragma unroll
        for (int m = 0; m < 4; ++m) {
          *(float4*)(Ls + (size_t)(ib + rr) * ND + ib + c4 + m * 4) =
              *(const float4*)&At[rr][c4 + m * 4];
          *(float4*)(q + rr * 64 + c4 + m * 4) = *(const float4*)&Bt[rr][c4 + m * 4];
        }
      }
      __syncthreads();
      RELF(bi * 18 + bi);
    } else {
      // off-diag: L(bi,bj) = acc @ iA(bj)^T
#pragma unroll
      for (int r = 0; r < 4; ++r)
#pragma unroll
        for (int e = 0; e < 4; ++e) At[tx * 4 + e][ty * 4 + r] = acc[r][e];
      WAITF(bj * 18 + bj);
      __syncthreads();
      {
        const float* q = iA64 + (size_t)(s * 18 + bj) * 4096;
        int a2 = tid >> 2, km = (tid & 3) * 4;
#pragma unroll
        for (int m = 0; m < 4; ++m) {
          float4 v = *(const float4*)(q + a2 * 64 + km + m * 16);
          Bt[km + m * 16 + 0][a2] = v.x;
          Bt[km + m * 16 + 1][a2] = v.y;
          Bt[km + m * 16 + 2][a2] = v.z;
          Bt[km + m * 16 + 3][a2] = v.w;
        }
      }
      __syncthreads();
      float acc2[4][4] = {};
#pragma unroll
      for (int kc = 0; kc < 64; ++kc) {
        float4 a4 = *(const float4*)&At[kc][ty * 4];
        float4 b4 = *(const float4*)&Bt[kc][tx * 4];
        float ar[4] = {a4.x, a4.y, a4.z, a4.w};
        float br[4] = {b4.x, b4.y, b4.z, b4.w};
#pragma unroll
        for (int r = 0; r < 4; ++r)
#pragma unroll
          for (int e = 0; e < 4; ++e) acc2[r][e] = fmaf(ar[r], br[e], acc2[r][e]);
      }
#pragma unroll
      for (int r = 0; r < 4; ++r) {
        float4 v = {acc2[r][0], acc2[r][1], acc2[r][2], acc2[r][3]};
        *(float4*)(Ls + (size_t)(ib + ty * 4 + r) * ND + jb + tx * 4) = v;
      }
      __syncthreads();
      RELF(bi * 18 + bj);
    }
    return;
  }

  if (t < 243) {
    // ---------------- forward solve, 64-row stage ----------------
    int u = t - 171;
    int r = u >> 2, ct = u & 3;
    int rb = r * 64, cb = ct * 64;
    float* Xfs = Xf + (size_t)s * ND * NCOUT;
    float acc[4][4];
#pragma unroll
    for (int rr = 0; rr < 4; ++rr) {
      size_t idx = (size_t)s * ND * NCOUT + (size_t)(rb + ty * 4 + rr) * NCOUT + cb + tx * 4;
      float4 v = *(const float4*)(B1 + idx);
      float4 v2 = *(const float4*)(B2 + idx);
      acc[rr][0] = v.x + v2.x; acc[rr][1] = v.y + v2.y;
      acc[rr][2] = v.z + v2.z; acc[rr][3] = v.w + v2.w;
    }
    for (int q = 0; q < r; ++q) {
      WAITF(324 + q * 4 + ct);
      WAITF(r * 18 + q);
      __syncthreads();
      int qb = q * 64;
      {  // At[k][i] = L[rb+i][qb+k]
        int i = tid >> 2, kb = (tid & 3) * 16;
        const float* src = Ls + (size_t)(rb + i) * ND + qb + kb;
#pragma unroll
        for (int m = 0; m < 4; ++m) {
          float4 v = *(const float4*)(src + m * 4);
          At[kb + m * 4 + 0][i] = v.x;
          At[kb + m * 4 + 1][i] = v.y;
          At[kb + m * 4 + 2][i] = v.z;
          At[kb + m * 4 + 3][i] = v.w;
        }
      }
      {  // Bt[k][j] = Xf[qb+k][cb+j]
        int k2 = tid >> 2, jb2 = (tid & 3) * 16;
        const float* src = Xfs + (size_t)(qb + k2) * NCOUT + cb + jb2;
#pragma unroll
        for (int m = 0; m < 4; ++m)
          *(float4*)&Bt[k2][jb2 + m * 4] = *(const float4*)(src + m * 4);
      }
      __syncthreads();
#pragma unroll
      for (int k = 0; k < 64; ++k) {
        float4 a4 = *(const float4*)&At[k][ty * 4];
        float4 b4 = *(const float4*)&Bt[k][tx * 4];
        float ar[4] = {a4.x, a4.y, a4.z, a4.w};
        float br[4] = {b4.x, b4.y, b4.z, b4.w};
#pragma unroll
        for (int rr = 0; rr < 4; ++rr)
#pragma unroll
          for (int e = 0; e < 4; ++e) acc[rr][e] = fmaf(-ar[rr], br[e], acc[rr][e]);
      }
      __syncthreads();
    }
    // diag: X(r) = iA64(r) @ acc
    WAITF(r * 18 + r);
    __syncthreads();
    {  // At[k][i] = iA[i][k]
      const float* q = iA64 + (size_t)(s * 18 + r) * 4096;
      int i = tid >> 2, kb = (tid & 3) * 16;
      const float* src = q + i * 64 + kb;
#pragma unroll
      for (int m = 0; m < 4; ++m) {
        float4 v = *(const float4*)(src + m * 4);
        At[kb + m * 4 + 0][i] = v.x;
        At[kb + m * 4 + 1][i] = v.y;
        At[kb + m * 4 + 2][i] = v.z;
        At[kb + m * 4 + 3][i] = v.w;
      }
    }
#pragma unroll
    for (int rr = 0; rr < 4; ++rr) {
      float4 v = {acc[rr][0], acc[rr][1], acc[rr][2], acc[rr][3]};
      *(float4*)&Bt[ty * 4 + rr][tx * 4] = v;
    }
    __syncthreads();
    float acc2[4][4] = {};
#pragma unroll
    for (int k = 0; k < 64; ++k) {
      float4 a4 = *(const float4*)&At[k][ty * 4];
      float4 b4 = *(const float4*)&Bt[k][tx * 4];
      float ar[4] = {a4.x, a4.y, a4.z, a4.w};
      float br[4] = {b4.x, b4.y, b4.z, b4.w};
#pragma unroll
      for (int rr = 0; rr < 4; ++rr)
#pragma unroll
        for (int e = 0; e < 4; ++e) acc2[rr][e] = fmaf(ar[rr], br[e], acc2[rr][e]);
    }
#pragma unroll
    for (int rr = 0; rr < 4; ++rr) {
      float4 v = {acc2[rr][0], acc2[rr][1], acc2[rr][2], acc2[rr][3]};
      *(float4*)(Xfs + (size_t)(rb + ty * 4 + rr) * NCOUT + cb + tx * 4) = v;
    }
    __syncthreads();
    RELF(324 + r * 4 + ct);
    return;
  }

  // ---------------- backward solve, 64-row stage (fused Z-add, Wm, sums) ----------------
  {
    int u = t - 243;
    int r = 17 - (u >> 2), ct = u & 3;
    int rb = r * 64, cb = ct * 64;
    float* Xfs = Xf + (size_t)s * ND * NCOUT;
    float* Xbs = Xb + (size_t)s * ND * NCOUT;

    WAITF(324 + r * 4 + ct);
    __syncthreads();
    float acc[4][4];
#pragma unroll
    for (int rr = 0; rr < 4; ++rr) {
      float4 v = *(const float4*)(Xfs + (size_t)(rb + ty * 4 + rr) * NCOUT + cb + tx * 4);
      acc[rr][0] = v.x; acc[rr][1] = v.y; acc[rr][2] = v.z; acc[rr][3] = v.w;
    }
    // add Z^T tile + zsum
    float zp = 0.f;
    {
      int c = tid & 63, dblk = (tid >> 6) * 16;
      const float* src = Z + ((size_t)(s * NCOUT) + cb + c) * ND + rb + dblk;
#pragma unroll
      for (int m = 0; m < 4; ++m) {
        float4 v = *(const float4*)(src + m * 4);
        At[dblk + m * 4 + 0][c] = v.x;
        At[dblk + m * 4 + 1][c] = v.y;
        At[dblk + m * 4 + 2][c] = v.z;
        At[dblk + m * 4 + 3][c] = v.w;
        zp += v.x * v.x + v.y * v.y + v.z * v.z + v.w * v.w;
      }
    }
    __syncthreads();
#pragma unroll
    for (int rr = 0; rr < 4; ++rr) {
      acc[rr][0] += At[ty * 4 + rr][tx * 4 + 0];
      acc[rr][1] += At[ty * 4 + rr][tx * 4 + 1];
      acc[rr][2] += At[ty * 4 + rr][tx * 4 + 2];
      acc[rr][3] += At[ty * 4 + rr][tx * 4 + 3];
    }
#pragma unroll
    for (int m2 = 32; m2 >= 1; m2 >>= 1) zp += __shfl_xor(zp, m2, 64);
    if (lane == 0) red[w] = zp;
    __syncthreads();
    if (tid == 0) atomicAdd(pp + s, red[0] + red[1] + red[2] + red[3]);

    for (int q = 17; q > r; --q) {
      WAITF(396 + q * 4 + ct);
      WAITF(q * 18 + r);
      __syncthreads();
      int qb = q * 64;
      {  // At[k][i] = L[qb+k][rb+i] (natural)
        int k2 = tid >> 2, ib2 = (tid & 3) * 16;
        const float* src = Ls + (size_t)(qb + k2) * ND + rb + ib2;
#pragma unroll
        for (int m = 0; m < 4; ++m)
          *(float4*)&At[k2][ib2 + m * 4] = *(const float4*)(src + m * 4);
      }
      {  // Bt[k][j] = Xb[qb+k][cb+j]
        int k2 = tid >> 2, jb2 = (tid & 3) * 16;
        const float* src = Xbs + (size_t)(qb + k2) * NCOUT + cb + jb2;
#pragma unroll
        for (int m = 0; m < 4; ++m)
          *(float4*)&Bt[k2][jb2 + m * 4] = *(const float4*)(src + m * 4);
      }
      __syncthreads();
#pragma unroll
      for (int k = 0; k < 64; ++k) {
        float4 a4 = *(const float4*)&At[k][ty * 4];
        float4 b4 = *(const float4*)&Bt[k][tx * 4];
        float ar[4] = {a4.x, a4.y, a4.z, a4.w};
        float br[4] = {b4.x, b4.y, b4.z, b4.w};
#pragma unroll
        for (int rr = 0; rr < 4; ++rr)
#pragma unroll
          for (int e = 0; e < 4; ++e) acc[rr][e] = fmaf(-ar[rr], br[e], acc[rr][e]);
      }
      __syncthreads();
    }
    // diag: X(r) = iA64(r)^T @ acc
    WAITF(r * 18 + r);
    __syncthreads();
    {  // At[k][i] = iA[k][i] (natural)
      const float* q = iA64 + (size_t)(s * 18 + r) * 4096;
      int k2 = tid >> 2, ib2 = (tid & 3) * 16;
      const float* src = q + k2 * 64 + ib2;
#pragma unroll
      for (int m = 0; m < 4; ++m)
        *(float4*)&At[k2][ib2 + m * 4] = *(const float4*)(src + m * 4);
    }
#pragma unroll
    for (int rr = 0; rr < 4; ++rr) {
      float4 v = {acc[rr][0], acc[rr][1], acc[rr][2], acc[rr][3]};
      *(float4*)&Bt[ty * 4 + rr][tx * 4] = v;
    }
    __syncthreads();
    float acc2[4][4] = {};
#pragma unroll
    for (int k = 0; k < 64; ++k) {
      float4 a4 = *(const float4*)&At[k][ty * 4];
      float4 b4 = *(const float4*)&Bt[k][tx * 4];
      float ar[4] = {a4.x, a4.y, a4.z, a4.w};
      float br[4] = {b4.x, b4.y, b4.z, b4.w};
#pragma unroll
      for (int rr = 0; rr < 4; ++rr)
#pragma unroll
        for (int e = 0; e < 4; ++e) acc2[rr][e] = fmaf(ar[rr], br[e], acc2[rr][e]);
    }
#pragma unroll
    for (int rr = 0; rr < 4; ++rr) {
      float4 v = {acc2[rr][0], acc2[rr][1], acc2[rr][2], acc2[rr][3]};
      *(float4*)(Xbs + (size_t)(rb + ty * 4 + rr) * NCOUT + cb + tx * 4) = v;
    }
    __syncthreads();
    RELF(396 + r * 4 + ct);
    // wsum
    float wp = 0.f;
#pragma unroll
    for (int rr = 0; rr < 4; ++rr)
#pragma unroll
      for (int e = 0; e < 4; ++e) wp += acc2[rr][e] * acc2[rr][e];
#pragma unroll
    for (int m2 = 32; m2 >= 1; m2 >>= 1) wp += __shfl_xor(wp, m2, 64);
    __syncthreads();
    if (lane == 0) red[w] = wp;
    __syncthreads();
    if (tid == 0) atomicAdd(pp + 4 + s, red[0] + red[1] + red[2] + red[3]);
    // Wm[s][c][d] = acc2[d][c] via LDS transpose
#pragma unroll
    for (int rr = 0; rr < 4; ++rr) {
      float4 v = {acc2[rr][0], acc2[rr][1], acc2[rr][2], acc2[rr][3]};
      *(float4*)&At[ty * 4 + rr][tx * 4] = v;
    }
    __syncthreads();
    {
      int c = tid & 63, dblk = (tid >> 6) * 16;
      float* dst = Wm + ((size_t)(s * NCOUT) + cb + c) * ND + rb + dblk;
#pragma unroll
      for (int m = 0; m < 4; ++m) {
        float4 v = {At[dblk + m * 4 + 0][c], At[dblk + m * 4 + 1][c],
                    At[dblk + m * 4 + 2][c], At[dblk + m * 4 + 3][c]};
        *(float4*)(dst + m * 4) = v;
      }
    }
  }
#undef WAITF
#undef RELF
}

__global__ __launch_bounds__(256) void k_finalize(const float* __restrict__ logd,
                                                  const float* __restrict__ pp,
                                                  float* __restrict__ out) {
  int s = blockIdx.x, tid = threadIdx.x;
  __shared__ float r0[256];
  float l = 0.f;
  for (int i = tid; i < ND; i += 256) l += logd[s * ND + i];
  r0[tid] = l;
  __syncthreads();
  for (int off = 128; off; off >>= 1) {
    if (tid < off) r0[tid] += r0[tid + off];
    __syncthreads();
  }
  if (tid == 0) {
    float logdet = 2.0f * r0[0];
    out[s] = 0.5f * (pp[s] - pp[4 + s]) - 128.0f * logdet;
  }
}

// ---------------- launcher ----------------
extern "C" void kernel_launch(void* const* d_in, const int* in_sizes, int n_in,
                              void* d_out, int out_size, void* d_ws, size_t ws_size,
                              hipStream_t stream) {
  const float* X = (const float*)d_in[0];
  const float* u = (const float*)d_in[1];
  const float* lp = (const float*)d_in[2];
  const float* Z = (const float*)d_in[3];
  float* out = (float*)d_out;

  float* ws = (float*)d_ws;
  float* sp    = ws;                                    // 64
  float* logd  = sp + 64;                               // 4608
  float* pp    = logd + (size_t)NS * ND;                // 64
  int*   flags = (int*)(pp + 64);                       // 2048 ints (1872 used)
  float* iA64  = (float*)(flags + 2048);                // 4*18*4096
  float* Xf    = iA64 + (size_t)NS * 18 * 4096;         // 4*1152*256
  float* Xb    = Xf + (size_t)NS * ND * NCOUT;          // 4*1152*256
  float* prec  = Xb + (size_t)NS * ND * NCOUT;          // 4*1152*1152
  float* prec2 = prec + (size_t)NS * D2;                // 4*1152*1152
  float* XLY   = prec2 + (size_t)NS * D2;               // 4*1152*256
  float* XLY2  = XLY + (size_t)NS * ND * NCOUT;         // 4*1152*256
  unsigned short* Phi = (unsigned short*)(XLY2 + (size_t)NS * ND * NCOUT);
  unsigned short* Plo = Phi + (size_t)NS * ND * NK;
  unsigned short* Yhi = Plo + (size_t)NS * ND * NK;
  unsigned short* Ylo = Yhi + (size_t)NCOUT * NK;

  hipMemsetAsync(flags, 0, 2048 * sizeof(int), stream);
  k_sqrtp<<<1, 64, 0, stream>>>(lp, sp, pp);
  k_patches<<<dim3(ND, NS), 128, 0, stream>>>(X, sp, Phi, Plo);
  k_ytt<<<NCOUT, 128, 0, stream>>>(u, sp, Yhi, Ylo);
  k_gemm_mfma<<<dim3(11, 9, NS * 2), 256, 0, stream>>>(Phi, Plo, Yhi, Ylo, prec,
                                                       prec2, XLY, XLY2);
  k_dag<<<315 * NS, 256, 0, stream>>>(prec, prec2, XLY, XLY2, Z, iA64, logd, Xf,
                                      Xb, out, pp, flags);
  k_finalize<<<NS, 256, 0, stream>>>(logd, pp, out + (size_t)NS * NCOUT * ND);
}

// Round 8
// 2565.631 us; speedup vs baseline: 1.0613x; 1.0613x over previous
//
#include <hip/hip_runtime.h>
#include <math.h>

#define NS 4
#define NB 32
#define CIN 128
#define NCOUT 256
#define HWN 256
#define ND 1152
#define NK 8192   // NB*HWN
static const size_t D2 = (size_t)ND * ND;

typedef __attribute__((ext_vector_type(8))) short bf16x8;
typedef __attribute__((ext_vector_type(4))) float f32x4;

static __device__ inline unsigned short f2bf(float x) {
  unsigned int u = __float_as_uint(x);
  unsigned int r = (u + 0x7fffu + ((u >> 16) & 1u)) >> 16;
  return (unsigned short)r;
}
static __device__ inline float bf2f(unsigned short h) {
  return __uint_as_float(((unsigned int)h) << 16);
}

// ---------------- small prep kernels ----------------

__global__ void k_sqrtp(const float* __restrict__ lp, float* __restrict__ sp,
                        float* __restrict__ pp) {
  int b = threadIdx.x;
  if (b < NB) sp[b] = expf(0.5f * lp[b]);
  if (b < 8) pp[b] = 0.f;
}

__global__ __launch_bounds__(128) void k_patches(const float* __restrict__ X,
                                                 const float* __restrict__ sp,
                                                 unsigned short* __restrict__ Phi,
                                                 unsigned short* __restrict__ Plo) {
  int d = blockIdx.x, s = blockIdx.y, t = threadIdx.x;
  int c = d / 9, r = d % 9, ky = r / 3, kx = r % 3;
  int p0 = t * 2;
  int yy = (p0 >> 4) + ky - 1;
  int xx0 = (p0 & 15) + kx - 1;
  bool oky = (yy >= 0 && yy < 16);
  bool ok0 = oky && (xx0 >= 0) && (xx0 < 16);
  bool ok1 = oky && (xx0 + 1 >= 0) && (xx0 + 1 < 16);
  int xo = yy * 16 + xx0;
  size_t base = ((size_t)s * ND + d) * NK + p0;
  for (int b = 0; b < NB; ++b) {
    float sb = sp[b];
    const float* xb = X + ((size_t)(s * NB + b) * CIN + c) * HWN;
    float v0 = ok0 ? xb[xo] * sb : 0.f;
    float v1 = ok1 ? xb[xo + 1] * sb : 0.f;
    unsigned short h0 = f2bf(v0), h1 = f2bf(v1);
    unsigned short l0 = f2bf(v0 - bf2f(h0)), l1 = f2bf(v1 - bf2f(h1));
    size_t idx = base + (size_t)b * HWN;
    *(unsigned int*)(Phi + idx) = (unsigned int)h0 | ((unsigned int)h1 << 16);
    *(unsigned int*)(Plo + idx) = (unsigned int)l0 | ((unsigned int)l1 << 16);
  }
}

__global__ __launch_bounds__(128) void k_ytt(const float* __restrict__ u,
                                             const float* __restrict__ sp,
                                             unsigned short* __restrict__ Yhi,
                                             unsigned short* __restrict__ Ylo) {
  int c = blockIdx.x, t = threadIdx.x;
  int p0 = t * 2;
  for (int b = 0; b < NB; ++b) {
    float sb = sp[b];
    const float* ub = u + ((size_t)b * NCOUT + c) * HWN + p0;
    float v0 = ub[0] * sb, v1 = ub[1] * sb;
    unsigned short h0 = f2bf(v0), h1 = f2bf(v1);
    unsigned short l0 = f2bf(v0 - bf2f(h0)), l1 = f2bf(v1 - bf2f(h1));
    size_t idx = (size_t)c * NK + (size_t)b * HWN + p0;
    *(unsigned int*)(Yhi + idx) = (unsigned int)h0 | ((unsigned int)h1 << 16);
    *(unsigned int*)(Ylo + idx) = (unsigned int)l0 | ((unsigned int)l1 << 16);
  }
}

// ---------------- bf16x3 MFMA XLX/XLY, K-split by 2 (partial sums) ----------------
__global__ __launch_bounds__(256) void k_gemm_mfma(
    const unsigned short* __restrict__ Phi, const unsigned short* __restrict__ Plo,
    const unsigned short* __restrict__ Yhi, const unsigned short* __restrict__ Ylo,
    float* __restrict__ prec, float* __restrict__ prec2,
    float* __restrict__ XLY, float* __restrict__ XLY2) {
  int jt = blockIdx.x, it = blockIdx.y;
  int s = blockIdx.z >> 1, kp = blockIdx.z & 1;
  bool isX = (jt <= it);
  if (!isX && jt < 9) return;
  int i0 = it * 128;
  int j0;
  const unsigned short *Bh, *Bl;
  if (isX) {
    j0 = jt * 128;
    Bh = Phi + ((size_t)s * ND + j0) * NK;
    Bl = Plo + ((size_t)s * ND + j0) * NK;
  } else {
    j0 = (jt - 9) * 128;
    Bh = Yhi + (size_t)j0 * NK;
    Bl = Ylo + (size_t)j0 * NK;
  }
  const unsigned short* Ah = Phi + ((size_t)s * ND + i0) * NK;
  const unsigned short* Al = Plo + ((size_t)s * ND + i0) * NK;

  __shared__ unsigned short sAh[4096], sAl[4096], sBh[4096], sBl[4096];
  int tid = threadIdx.x, wave = tid >> 6, lane = tid & 63;
  int wr = wave >> 1, wc = wave & 1;

  f32x4 zero = {0.f, 0.f, 0.f, 0.f};
  f32x4 acc[4][4];
#pragma unroll
  for (int m = 0; m < 4; ++m)
#pragma unroll
    for (int n = 0; n < 4; ++n) acc[m][n] = zero;

  const unsigned short* srcs[4] = {Ah, Al, Bh, Bl};
  unsigned short* dsts[4] = {sAh, sAl, sBh, sBl};
  int r0l = lane >> 2;
  int ke = (lane & 3) * 8;
  int arow0 = wr * 64 + (lane & 15);
  int brow0 = wc * 64 + (lane & 15);
  int koff = (lane >> 4) * 8;

  int kbeg = kp * (NK / 2), kend = kbeg + NK / 2;
  for (int k0 = kbeg; k0 < kend; k0 += 32) {
    __syncthreads();
#pragma unroll
    for (int f = 0; f < 4; ++f) {
#pragma unroll
      for (int cc = 0; cc < 2; ++cc) {
        int c = wave * 2 + cc;
        const unsigned short* g = srcs[f] + (size_t)(c * 16 + r0l) * NK + k0 + ke;
        unsigned short* l = dsts[f] + c * 512;
        __builtin_amdgcn_global_load_lds(
            (const __attribute__((address_space(1))) void*)g,
            (__attribute__((address_space(3))) void*)l, 16, 0, 0);
      }
    }
    __syncthreads();
    bf16x8 ah[4], al[4], bh[4], bl[4];
#pragma unroll
    for (int m = 0; m < 4; ++m) {
      int off = (arow0 + m * 16) * 32 + koff;
      ah[m] = *(const bf16x8*)&sAh[off];
      al[m] = *(const bf16x8*)&sAl[off];
    }
#pragma unroll
    for (int n = 0; n < 4; ++n) {
      int off = (brow0 + n * 16) * 32 + koff;
      bh[n] = *(const bf16x8*)&sBh[off];
      bl[n] = *(const bf16x8*)&sBl[off];
    }
#pragma unroll
    for (int m = 0; m < 4; ++m)
#pragma unroll
      for (int n = 0; n < 4; ++n) {
        acc[m][n] = __builtin_amdgcn_mfma_f32_16x16x32_bf16(ah[m], bh[n], acc[m][n], 0, 0, 0);
        acc[m][n] = __builtin_amdgcn_mfma_f32_16x16x32_bf16(ah[m], bl[n], acc[m][n], 0, 0, 0);
        acc[m][n] = __builtin_amdgcn_mfma_f32_16x16x32_bf16(al[m], bh[n], acc[m][n], 0, 0, 0);
      }
  }

  if (isX) {
    float* base = (kp ? prec2 : prec) + (size_t)s * D2;
#pragma unroll
    for (int m = 0; m < 4; ++m) {
      int row = i0 + wr * 64 + m * 16 + (lane >> 4) * 4;
#pragma unroll
      for (int n = 0; n < 4; ++n) {
        int col = j0 + wc * 64 + n * 16 + (lane & 15);
        float* cp = base + (size_t)row * ND + col;
#pragma unroll
        for (int r = 0; r < 4; ++r) cp[(size_t)r * ND] = acc[m][n][r];
      }
    }
  } else {
    float* base = (kp ? XLY2 : XLY) + (size_t)s * ND * NCOUT;
#pragma unroll
    for (int m = 0; m < 4; ++m) {
      int row = i0 + wr * 64 + m * 16 + (lane >> 4) * 4;
#pragma unroll
      for (int n = 0; n < 4; ++n) {
        int col = j0 + wc * 64 + n * 16 + (lane & 15);
        float* cp = base + (size_t)row * NCOUT + col;
#pragma unroll
        for (int r = 0; r < 4; ++r) cp[(size_t)r * NCOUT] = acc[m][n][r];
      }
    }
  }
}

// ================ persistent DAG Cholesky, 128x128 tiles ================
// grid (45, NS): tile (bi,bj) lower 9x9, flags fc[s*81 + bi*9 + bj].
// Diag tiles: fused wave-shuffle factor+inverse of both 64-diagonals, in-block
// trsm/Schur, publish L and full 128x128 inverse iD = [[iA,0],[-iC*B*iA, iC]].
// Off-diag: updates + trsm against iD(bj). 180 blocks, all co-resident.
__global__ __launch_bounds__(256) void k_chol128(
    float* __restrict__ L, const float* __restrict__ Lp2,
    float* __restrict__ iD, float* __restrict__ logd, int* __restrict__ flags) {
  int t = blockIdx.x, s = blockIdx.y;
  int bi = 0;
  while ((bi + 1) * (bi + 2) / 2 <= t) ++bi;
  int bj = t - bi * (bi + 1) / 2;
  int ib = bi * 128, jb = bj * 128;
  float* Ls = L + (size_t)s * D2;
  const float* Ps = Lp2 + (size_t)s * D2;
  int* fc = flags + s * 81;
  int tid = threadIdx.x, tx = tid & 15, ty = tid >> 4;
  int lane = tid & 63, w = tid >> 6;

  __shared__ float SH[13056];                     // 51 KB, phase-aliased
  float (*At)[132] = (float(*)[132])SH;           // 32x132 (update/trsm)
  float (*Bt)[132] = (float(*)[132])(SH + 4224);  // 32x132
  float (*T1)[68] = (float(*)[68])SH;             // 64x68 (diag phase)
  float (*T2)[68] = (float(*)[68])(SH + 4352);
  float (*T3)[68] = (float(*)[68])(SH + 8704);

  // acc[rr][cc] = tile[ty*8+rr][tx*8+cc] = prec + prec2 (+I on diag)
  float acc[8][8];
#pragma unroll
  for (int rr = 0; rr < 8; ++rr) {
    size_t idx = (size_t)(ib + ty * 8 + rr) * ND + jb + tx * 8;
    float4 v0 = *(const float4*)(Ls + idx);
    float4 v1 = *(const float4*)(Ls + idx + 4);
    float4 p0 = *(const float4*)(Ps + idx);
    float4 p1 = *(const float4*)(Ps + idx + 4);
    acc[rr][0] = v0.x + p0.x; acc[rr][1] = v0.y + p0.y;
    acc[rr][2] = v0.z + p0.z; acc[rr][3] = v0.w + p0.w;
    acc[rr][4] = v1.x + p1.x; acc[rr][5] = v1.y + p1.y;
    acc[rr][6] = v1.z + p1.z; acc[rr][7] = v1.w + p1.w;
  }
  if (bi == bj) {
#pragma unroll
    for (int rr = 0; rr < 8; ++rr)
#pragma unroll
      for (int cc = 0; cc < 8; ++cc)
        if (ty * 8 + rr == tx * 8 + cc) acc[rr][cc] += 1.f;
  }

  // trailing updates: acc -= L(bi,k) @ L(bj,k)^T
  for (int k = 0; k < bj; ++k) {
    if (tid == 0) {
      while (__hip_atomic_load(&fc[bi * 9 + k], __ATOMIC_RELAXED,
                               __HIP_MEMORY_SCOPE_AGENT) == 0)
        __builtin_amdgcn_s_sleep(2);
      while (__hip_atomic_load(&fc[bj * 9 + k], __ATOMIC_RELAXED,
                               __HIP_MEMORY_SCOPE_AGENT) == 0)
        __builtin_amdgcn_s_sleep(2);
      (void)__hip_atomic_load(&fc[bj * 9 + k], __ATOMIC_ACQUIRE,
                              __HIP_MEMORY_SCOPE_AGENT);
    }
    __syncthreads();
    int kb = k * 128;
#pragma unroll 1
    for (int kc = 0; kc < 4; ++kc) {
      int i2 = tid >> 1, ko = (tid & 1) * 16;
      const float* sa = Ls + (size_t)(ib + i2) * ND + kb + kc * 32 + ko;
      const float* sbp = Ls + (size_t)(jb + i2) * ND + kb + kc * 32 + ko;
#pragma unroll
      for (int m = 0; m < 4; ++m) {
        float4 v = *(const float4*)(sa + m * 4);
        At[ko + m * 4 + 0][i2] = v.x;
        At[ko + m * 4 + 1][i2] = v.y;
        At[ko + m * 4 + 2][i2] = v.z;
        At[ko + m * 4 + 3][i2] = v.w;
        float4 u4 = *(const float4*)(sbp + m * 4);
        Bt[ko + m * 4 + 0][i2] = u4.x;
        Bt[ko + m * 4 + 1][i2] = u4.y;
        Bt[ko + m * 4 + 2][i2] = u4.z;
        Bt[ko + m * 4 + 3][i2] = u4.w;
      }
      __syncthreads();
#pragma unroll 8
      for (int kk = 0; kk < 32; ++kk) {
        float4 a0 = *(const float4*)&At[kk][ty * 8];
        float4 a1 = *(const float4*)&At[kk][ty * 8 + 4];
        float4 b0 = *(const float4*)&Bt[kk][tx * 8];
        float4 b1 = *(const float4*)&Bt[kk][tx * 8 + 4];
        float a8[8] = {a0.x, a0.y, a0.z, a0.w, a1.x, a1.y, a1.z, a1.w};
        float b8[8] = {b0.x, b0.y, b0.z, b0.w, b1.x, b1.y, b1.z, b1.w};
#pragma unroll
        for (int rr = 0; rr < 8; ++rr)
#pragma unroll
          for (int cc = 0; cc < 8; ++cc)
            acc[rr][cc] = fmaf(-a8[rr], b8[cc], acc[rr][cc]);
      }
      __syncthreads();
    }
  }

  if (bi != bj) {
    // ---- trsm: o = acc @ iD(bj)^T ----
    const float* iq = iD + ((size_t)(s * 9 + bj)) * 16384;
    if (tid == 0) {
      while (__hip_atomic_load(&fc[bj * 9 + bj], __ATOMIC_RELAXED,
                               __HIP_MEMORY_SCOPE_AGENT) == 0)
        __builtin_amdgcn_s_sleep(2);
      (void)__hip_atomic_load(&fc[bj * 9 + bj], __ATOMIC_ACQUIRE,
                              __HIP_MEMORY_SCOPE_AGENT);
    }
    __syncthreads();
    float o[8][8] = {};
#pragma unroll 1
    for (int kc = 0; kc < 4; ++kc) {
      if ((tx >> 2) == kc) {  // stage acc cols [kc*32, kc*32+32) as At[k][i]
        int kbase = tx * 8 - kc * 32;
#pragma unroll
        for (int cc = 0; cc < 8; ++cc)
#pragma unroll
          for (int rr = 0; rr < 8; ++rr)
            At[kbase + cc][ty * 8 + rr] = acc[rr][cc];
      }
      {
        int j2 = tid >> 1, ko = (tid & 1) * 16;
        const float* sbp = iq + (size_t)j2 * 128 + kc * 32 + ko;
#pragma unroll
        for (int m = 0; m < 4; ++m) {
          float4 v = *(const float4*)(sbp + m * 4);
          Bt[ko + m * 4 + 0][j2] = v.x;
          Bt[ko + m * 4 + 1][j2] = v.y;
          Bt[ko + m * 4 + 2][j2] = v.z;
          Bt[ko + m * 4 + 3][j2] = v.w;
        }
      }
      __syncthreads();
#pragma unroll 8
      for (int kk = 0; kk < 32; ++kk) {
        float4 a0 = *(const float4*)&At[kk][ty * 8];
        float4 a1 = *(const float4*)&At[kk][ty * 8 + 4];
        float4 b0 = *(const float4*)&Bt[kk][tx * 8];
        float4 b1 = *(const float4*)&Bt[kk][tx * 8 + 4];
        float a8[8] = {a0.x, a0.y, a0.z, a0.w, a1.x, a1.y, a1.z, a1.w};
        float b8[8] = {b0.x, b0.y, b0.z, b0.w, b1.x, b1.y, b1.z, b1.w};
#pragma unroll
        for (int rr = 0; rr < 8; ++rr)
#pragma unroll
          for (int cc = 0; cc < 8; ++cc)
            o[rr][cc] = fmaf(a8[rr], b8[cc], o[rr][cc]);
      }
      __syncthreads();
    }
#pragma unroll
    for (int rr = 0; rr < 8; ++rr) {
      size_t idx = (size_t)(ib + ty * 8 + rr) * ND + jb + tx * 8;
      float4 v0 = {o[rr][0], o[rr][1], o[rr][2], o[rr][3]};
      float4 v1 = {o[rr][4], o[rr][5], o[rr][6], o[rr][7]};
      *(float4*)(Ls + idx) = v0;
      *(float4*)(Ls + idx + 4) = v1;
    }
    __syncthreads();
    if (tid == 0)
      __hip_atomic_store(&fc[bi * 9 + bj], 1, __ATOMIC_RELEASE,
                         __HIP_MEMORY_SCOPE_AGENT);
    return;
  }

  // ---- diag tile: factor 128x128 + full inverse ----
  float* iq = iD + ((size_t)(s * 9 + bi)) * 16384;
  // D1: dump A11 quadrant
  if (ty < 8 && tx < 8) {
#pragma unroll
    for (int rr = 0; rr < 8; ++rr) {
      float4 v0 = {acc[rr][0], acc[rr][1], acc[rr][2], acc[rr][3]};
      float4 v1 = {acc[rr][4], acc[rr][5], acc[rr][6], acc[rr][7]};
      *(float4*)&T1[ty * 8 + rr][tx * 8] = v0;
      *(float4*)&T1[ty * 8 + rr][tx * 8 + 4] = v1;
    }
  }
  __syncthreads();
  // D2: wave0 factors A11 + inverse (iA -> T2)
  if (w == 0) {
    float a[64], x[64];
#pragma unroll
    for (int tt2 = 0; tt2 < 64; ++tt2) {
      a[tt2] = T1[lane][tt2];
      x[tt2] = (tt2 == lane) ? 1.f : 0.f;
    }
    float diagv = 1.f;
#pragma unroll
    for (int j = 0; j < 64; ++j) {
      float dj = __shfl(a[j], j, 64);
      float rinv = 1.0f / sqrtf(dj);
      a[j] *= rinv;
      x[j] *= rinv;
      if (lane == j) diagv = a[j];
#pragma unroll
      for (int tt2 = j + 1; tt2 < 64; ++tt2) {
        float ltj = __shfl(a[j], tt2, 64);
        a[tt2] = fmaf(-a[j], ltj, a[tt2]);
        x[tt2] = fmaf(-x[j], ltj, x[tt2]);
      }
    }
#pragma unroll
    for (int tt2 = 0; tt2 < 64; ++tt2) T1[lane][tt2] = (tt2 <= lane) ? a[tt2] : 0.f;
#pragma unroll
    for (int i = 0; i < 64; ++i) T2[i][lane] = x[i];
    logd[s * ND + ib + lane] = logf(diagv);
  }
  __syncthreads();
  // D3: persist L11, iA(+zero right half); dump A21 -> T3
  {
    int r2 = tid >> 2, c4a = (tid & 3) * 16;
#pragma unroll
    for (int m = 0; m < 4; ++m) {
      *(float4*)(Ls + (size_t)(ib + r2) * ND + ib + c4a + m * 4) =
          *(const float4*)&T1[r2][c4a + m * 4];
      *(float4*)(iq + (size_t)r2 * 128 + c4a + m * 4) =
          *(const float4*)&T2[r2][c4a + m * 4];
      float4 z = {0.f, 0.f, 0.f, 0.f};
      *(float4*)(iq + (size_t)r2 * 128 + 64 + c4a + m * 4) = z;
    }
  }
  if (ty >= 8 && tx < 8) {
#pragma unroll
    for (int rr = 0; rr < 8; ++rr) {
      float4 v0 = {acc[rr][0], acc[rr][1], acc[rr][2], acc[rr][3]};
      float4 v1 = {acc[rr][4], acc[rr][5], acc[rr][6], acc[rr][7]};
      *(float4*)&T3[(ty - 8) * 8 + rr][tx * 8] = v0;
      *(float4*)&T3[(ty - 8) * 8 + rr][tx * 8 + 4] = v1;
    }
  }
  __syncthreads();
  int i4 = ty * 4, j4 = tx * 4;
  // D4: L21 = A21 @ iA^T (in T3)
  {
    float l21r[4][4] = {};
#pragma unroll 4
    for (int k2 = 0; k2 < 64; ++k2) {
      float a4[4], b4[4];
#pragma unroll
      for (int e = 0; e < 4; ++e) { a4[e] = T3[i4 + e][k2]; b4[e] = T2[j4 + e][k2]; }
#pragma unroll
      for (int rr = 0; rr < 4; ++rr)
#pragma unroll
        for (int cc = 0; cc < 4; ++cc) l21r[rr][cc] = fmaf(a4[rr], b4[cc], l21r[rr][cc]);
    }
    __syncthreads();
#pragma unroll
    for (int rr = 0; rr < 4; ++rr)
#pragma unroll
      for (int cc = 0; cc < 4; ++cc) T3[i4 + rr][j4 + cc] = l21r[rr][cc];
  }
  __syncthreads();
  // D5: persist L21; dump A22 -> T1
  {
    int r2 = tid >> 2, c4a = (tid & 3) * 16;
#pragma unroll
    for (int m = 0; m < 4; ++m)
      *(float4*)(Ls + (size_t)(ib + 64 + r2) * ND + ib + c4a + m * 4) =
          *(const float4*)&T3[r2][c4a + m * 4];
  }
  if (ty >= 8 && tx >= 8) {
#pragma unroll
    for (int rr = 0; rr < 8; ++rr) {
      float4 v0 = {acc[rr][0], acc[rr][1], acc[rr][2], acc[rr][3]};
      float4 v1 = {acc[rr][4], acc[rr][5], acc[rr][6], acc[rr][7]};
      *(float4*)&T1[(ty - 8) * 8 + rr][(tx - 8) * 8] = v0;
      *(float4*)&T1[(ty - 8) * 8 + rr][(tx - 8) * 8 + 4] = v1;
    }
  }
  __syncthreads();
  // D5c: Schur C = A22 - L21 @ L21^T (in T1)
  {
    float s4[4][4] = {};
#pragma unroll 4
    for (int k2 = 0; k2 < 64; ++k2) {
      float a4[4], b4[4];
#pragma unroll
      for (int e = 0; e < 4; ++e) { a4[e] = T3[i4 + e][k2]; b4[e] = T3[j4 + e][k2]; }
#pragma unroll
      for (int rr = 0; rr < 4; ++rr)
#pragma unroll
        for (int cc = 0; cc < 4; ++cc) s4[rr][cc] = fmaf(a4[rr], b4[cc], s4[rr][cc]);
    }
#pragma unroll
    for (int rr = 0; rr < 4; ++rr)
#pragma unroll
      for (int cc = 0; cc < 4; ++cc) T1[i4 + rr][j4 + cc] -= s4[rr][cc];
  }
  __syncthreads();
  // D5.5: Tm = L21 @ iA (overwrite T3)
  {
    float tm[4][4] = {};
#pragma unroll 4
    for (int k2 = 0; k2 < 64; ++k2) {
      float a4[4], b4[4];
#pragma unroll
      for (int e = 0; e < 4; ++e) { a4[e] = T3[i4 + e][k2]; b4[e] = T2[k2][j4 + e]; }
#pragma unroll
      for (int rr = 0; rr < 4; ++rr)
#pragma unroll
        for (int cc = 0; cc < 4; ++cc) tm[rr][cc] = fmaf(a4[rr], b4[cc], tm[rr][cc]);
    }
    __syncthreads();
#pragma unroll
    for (int rr = 0; rr < 4; ++rr)
#pragma unroll
      for (int cc = 0; cc < 4; ++cc) T3[i4 + rr][j4 + cc] = tm[rr][cc];
  }
  __syncthreads();
  // D6: wave0 factors C + inverse (iC -> T2, clobbering iA)
  if (w == 0) {
    float a[64], x[64];
#pragma unroll
    for (int tt2 = 0; tt2 < 64; ++tt2) {
      a[tt2] = T1[lane][tt2];
      x[tt2] = (tt2 == lane) ? 1.f : 0.f;
    }
    float diagv = 1.f;
#pragma unroll
    for (int j = 0; j < 64; ++j) {
      float dj = __shfl(a[j], j, 64);
      float rinv = 1.0f / sqrtf(dj);
      a[j] *= rinv;
      x[j] *= rinv;
      if (lane == j) diagv = a[j];
#pragma unroll
      for (int tt2 = j + 1; tt2 < 64; ++tt2) {
        float ltj = __shfl(a[j], tt2, 64);
        a[tt2] = fmaf(-a[j], ltj, a[tt2]);
        x[tt2] = fmaf(-x[j], ltj, x[tt2]);
      }
    }
#pragma unroll
    for (int tt2 = 0; tt2 < 64; ++tt2) T1[lane][tt2] = (tt2 <= lane) ? a[tt2] : 0.f;
#pragma unroll
    for (int i = 0; i < 64; ++i) T2[i][lane] = x[i];
    logd[s * ND + ib + 64 + lane] = logf(diagv);
  }
  __syncthreads();
  // D7: persist L22, iC; G = -iC @ Tm -> iD
  {
    int r2 = tid >> 2, c4a = (tid & 3) * 16;
#pragma unroll
    for (int m = 0; m < 4; ++m) {
      *(float4*)(Ls + (size_t)(ib + 64 + r2) * ND + ib + 64 + c4a + m * 4) =
          *(const float4*)&T1[r2][c4a + m * 4];
      *(float4*)(iq + (size_t)(64 + r2) * 128 + 64 + c4a + m * 4) =
          *(const float4*)&T2[r2][c4a + m * 4];
    }
  }
  {
    float g4[4][4] = {};
#pragma unroll 4
    for (int k2 = 0; k2 < 64; ++k2) {
      float a4[4], b4[4];
#pragma unroll
      for (int e = 0; e < 4; ++e) { a4[e] = T2[i4 + e][k2]; b4[e] = T3[k2][j4 + e]; }
#pragma unroll
      for (int rr = 0; rr < 4; ++rr)
#pragma unroll
        for (int cc = 0; cc < 4; ++cc) g4[rr][cc] = fmaf(a4[rr], b4[cc], g4[rr][cc]);
    }
#pragma unroll
    for (int rr = 0; rr < 4; ++rr) {
      float4 v = {-g4[rr][0], -g4[rr][1], -g4[rr][2], -g4[rr][3]};
      *(float4*)(iq + (size_t)(64 + i4 + rr) * 128 + j4) = v;
    }
  }
  __syncthreads();
  if (tid == 0)
    __hip_atomic_store(&fc[bi * 9 + bi], 1, __ATOMIC_RELEASE,
                       __HIP_MEMORY_SCOPE_AGENT);
}

// ---------------- merged persistent fwd+bwd solve (fused addz/writewm) ----------------
__global__ __launch_bounds__(256) void k_solve2(
    const float* __restrict__ L, const float* __restrict__ iD,
    const float* __restrict__ B1, const float* __restrict__ B2,
    const float* __restrict__ Z, float* __restrict__ Xf, float* __restrict__ Xb,
    float* __restrict__ Wm, float* __restrict__ pp, int* __restrict__ flags) {
  int r = blockIdx.x, ct = blockIdx.y, s = blockIdx.z;
  int rb = r * 128, cb = ct * 64;
  const float* Ls = L + (size_t)s * D2;
  const float* Dq = iD + ((size_t)(s * 9 + r)) * 16384;
  float* Xfs = Xf + (size_t)s * ND * NCOUT;
  float* Xbs = Xb + (size_t)s * ND * NCOUT;
  int fbf = 1296 + (s * 4 + ct) * 9;
  int fbb = 1440 + (s * 4 + ct) * 9;

  __shared__ float sA[32][132];
  __shared__ float sB[32][68];
  __shared__ float red[8];
  int tid = threadIdx.x, tx = tid & 15, ty = tid >> 4;
  int wave = tid >> 6, lane = tid & 63;

  // ======== forward ========
  float acc[8][4];
#pragma unroll
  for (int ii = 0; ii < 8; ++ii) {
    size_t idx = (size_t)s * ND * NCOUT + (size_t)(rb + ty * 8 + ii) * NCOUT + cb + tx * 4;
    float4 v = *(const float4*)(B1 + idx);
    float4 v2 = *(const float4*)(B2 + idx);
    acc[ii][0] = v.x + v2.x; acc[ii][1] = v.y + v2.y;
    acc[ii][2] = v.z + v2.z; acc[ii][3] = v.w + v2.w;
  }
  for (int q = 0; q < r; ++q) {
    if (tid == 0) {
      while (__hip_atomic_load(&flags[fbf + q], __ATOMIC_RELAXED,
                               __HIP_MEMORY_SCOPE_AGENT) == 0)
        __builtin_amdgcn_s_sleep(2);
      (void)__hip_atomic_load(&flags[fbf + q], __ATOMIC_ACQUIRE,
                              __HIP_MEMORY_SCOPE_AGENT);
    }
    __syncthreads();
    int qb = q * 128;
    for (int kk = 0; kk < 4; ++kk) {
      __syncthreads();
      {
        int i = tid >> 1, kb = (tid & 1) * 16;
        const float* src = Ls + (size_t)(rb + i) * ND + qb + kk * 32 + kb;
#pragma unroll
        for (int m = 0; m < 4; ++m) {
          float4 v = *(const float4*)(src + m * 4);
          sA[kb + m * 4 + 0][i] = v.x;
          sA[kb + m * 4 + 1][i] = v.y;
          sA[kb + m * 4 + 2][i] = v.z;
          sA[kb + m * 4 + 3][i] = v.w;
        }
      }
      {
        int k = tid >> 3, jb2 = (tid & 7) * 8;
        const float* src = Xfs + (size_t)(qb + kk * 32 + k) * NCOUT + cb + jb2;
        float4 v0 = *(const float4*)src;
        float4 v1 = *(const float4*)(src + 4);
        *(float4*)&sB[k][jb2] = v0;
        *(float4*)&sB[k][jb2 + 4] = v1;
      }
      __syncthreads();
#pragma unroll
      for (int k = 0; k < 32; ++k) {
        float4 a0 = *(const float4*)&sA[k][ty * 8];
        float4 a1 = *(const float4*)&sA[k][ty * 8 + 4];
        float4 b0 = *(const float4*)&sB[k][tx * 4];
        float a[8] = {a0.x, a0.y, a0.z, a0.w, a1.x, a1.y, a1.z, a1.w};
        float b[4] = {b0.x, b0.y, b0.z, b0.w};
#pragma unroll
        for (int ii = 0; ii < 8; ++ii)
#pragma unroll
          for (int j = 0; j < 4; ++j) acc[ii][j] = fmaf(-a[ii], b[j], acc[ii][j]);
      }
    }
  }
  float acc2[8][4] = {};
  for (int kk = 0; kk < 4; ++kk) {
    __syncthreads();
    if ((ty >> 2) == kk) {
      int kloc = ty * 8 - kk * 32;
#pragma unroll
      for (int ii = 0; ii < 8; ++ii) {
        float4 v = {acc[ii][0], acc[ii][1], acc[ii][2], acc[ii][3]};
        *(float4*)&sB[kloc + ii][tx * 4] = v;
      }
    }
    {
      int i = tid >> 1, kb = (tid & 1) * 16;
      const float* src = Dq + (size_t)i * 128 + kk * 32 + kb;
#pragma unroll
      for (int m = 0; m < 4; ++m) {
        float4 v = *(const float4*)(src + m * 4);
        sA[kb + m * 4 + 0][i] = v.x;
        sA[kb + m * 4 + 1][i] = v.y;
        sA[kb + m * 4 + 2][i] = v.z;
        sA[kb + m * 4 + 3][i] = v.w;
      }
    }
    __syncthreads();
#pragma unroll
    for (int k = 0; k < 32; ++k) {
      float4 a0 = *(const float4*)&sA[k][ty * 8];
      float4 a1 = *(const float4*)&sA[k][ty * 8 + 4];
      float4 b0 = *(const float4*)&sB[k][tx * 4];
      float a[8] = {a0.x, a0.y, a0.z, a0.w, a1.x, a1.y, a1.z, a1.w};
      float b[4] = {b0.x, b0.y, b0.z, b0.w};
#pragma unroll
      for (int ii = 0; ii < 8; ++ii)
#pragma unroll
        for (int j = 0; j < 4; ++j) acc2[ii][j] = fmaf(a[ii], b[j], acc2[ii][j]);
    }
  }
#pragma unroll
  for (int ii = 0; ii < 8; ++ii) {
    float4 v = {acc2[ii][0], acc2[ii][1], acc2[ii][2], acc2[ii][3]};
    *(float4*)(Xfs + (size_t)(rb + ty * 8 + ii) * NCOUT + cb + tx * 4) = v;
  }
  __threadfence();
  __syncthreads();
  if (tid == 0)
    __hip_atomic_store(&flags[fbf + r], 1, __ATOMIC_RELEASE,
                       __HIP_MEMORY_SCOPE_AGENT);

  // ======== backward (init from fwd result in registers) ========
#pragma unroll
  for (int ii = 0; ii < 8; ++ii)
#pragma unroll
    for (int j = 0; j < 4; ++j) acc[ii][j] = acc2[ii][j];

  float zp = 0.f;
  for (int kk = 0; kk < 4; ++kk) {
    __syncthreads();
    {
      int c = tid >> 2, d8 = (tid & 3) * 8;
      const float* src = Z + ((size_t)(s * NCOUT) + cb + c) * ND + rb + kk * 32 + d8;
      float4 v0 = *(const float4*)src;
      float4 v1 = *(const float4*)(src + 4);
      sA[d8 + 0][c] = v0.x; sA[d8 + 1][c] = v0.y; sA[d8 + 2][c] = v0.z; sA[d8 + 3][c] = v0.w;
      sA[d8 + 4][c] = v1.x; sA[d8 + 5][c] = v1.y; sA[d8 + 6][c] = v1.z; sA[d8 + 7][c] = v1.w;
      zp += v0.x * v0.x + v0.y * v0.y + v0.z * v0.z + v0.w * v0.w;
      zp += v1.x * v1.x + v1.y * v1.y + v1.z * v1.z + v1.w * v1.w;
    }
    __syncthreads();
    if ((ty >> 2) == kk) {
      int kloc = ty * 8 - kk * 32;
#pragma unroll
      for (int ii = 0; ii < 8; ++ii) {
        float4 v = *(const float4*)&sA[kloc + ii][tx * 4];
        acc[ii][0] += v.x; acc[ii][1] += v.y; acc[ii][2] += v.z; acc[ii][3] += v.w;
      }
    }
  }
#pragma unroll
  for (int m2 = 32; m2 >= 1; m2 >>= 1) zp += __shfl_xor(zp, m2, 64);
  if (lane == 0) red[wave] = zp;
  __syncthreads();
  if (tid == 0) atomicAdd(pp + s, red[0] + red[1] + red[2] + red[3]);

  for (int q = 8; q > r; --q) {
    if (tid == 0) {
      while (__hip_atomic_load(&flags[fbb + q], __ATOMIC_RELAXED,
                               __HIP_MEMORY_SCOPE_AGENT) == 0)
        __builtin_amdgcn_s_sleep(2);
      (void)__hip_atomic_load(&flags[fbb + q], __ATOMIC_ACQUIRE,
                              __HIP_MEMORY_SCOPE_AGENT);
    }
    __syncthreads();
    int qb = q * 128;
    for (int kk = 0; kk < 4; ++kk) {
      __syncthreads();
      {
        int k = tid >> 3, ib2 = (tid & 7) * 16;
        const float* src = Ls + (size_t)(qb + kk * 32 + k) * ND + rb + ib2;
#pragma unroll
        for (int m = 0; m < 4; ++m)
          *(float4*)&sA[k][ib2 + m * 4] = *(const float4*)(src + m * 4);
      }
      {
        int k = tid >> 3, jb2 = (tid & 7) * 8;
        const float* src = Xbs + (size_t)(qb + kk * 32 + k) * NCOUT + cb + jb2;
        float4 v0 = *(const float4*)src;
        float4 v1 = *(const float4*)(src + 4);
        *(float4*)&sB[k][jb2] = v0;
        *(float4*)&sB[k][jb2 + 4] = v1;
      }
      __syncthreads();
#pragma unroll
      for (int k = 0; k < 32; ++k) {
        float4 a0 = *(const float4*)&sA[k][ty * 8];
        float4 a1 = *(const float4*)&sA[k][ty * 8 + 4];
        float4 b0 = *(const float4*)&sB[k][tx * 4];
        float a[8] = {a0.x, a0.y, a0.z, a0.w, a1.x, a1.y, a1.z, a1.w};
        float b[4] = {b0.x, b0.y, b0.z, b0.w};
#pragma unroll
        for (int ii = 0; ii < 8; ++ii)
#pragma unroll
          for (int j = 0; j < 4; ++j) acc[ii][j] = fmaf(-a[ii], b[j], acc[ii][j]);
      }
    }
  }
#pragma unroll
  for (int ii = 0; ii < 8; ++ii)
#pragma unroll
    for (int j = 0; j < 4; ++j) acc2[ii][j] = 0.f;
  for (int kk = 0; kk < 4; ++kk) {
    __syncthreads();
    if ((ty >> 2) == kk) {
      int kloc = ty * 8 - kk * 32;
#pragma unroll
      for (int ii = 0; ii < 8; ++ii) {
        float4 v = {acc[ii][0], acc[ii][1], acc[ii][2], acc[ii][3]};
        *(float4*)&sB[kloc + ii][tx * 4] = v;
      }
    }
    {
      int k = tid >> 3, ib2 = (tid & 7) * 16;
      const float* src = Dq + (size_t)(kk * 32 + k) * 128 + ib2;
#pragma unroll
      for (int m = 0; m < 4; ++m)
        *(float4*)&sA[k][ib2 + m * 4] = *(const float4*)(src + m * 4);
    }
    __syncthreads();
#pragma unroll
    for (int k = 0; k < 32; ++k) {
      float4 a0 = *(const float4*)&sA[k][ty * 8];
      float4 a1 = *(const float4*)&sA[k][ty * 8 + 4];
      float4 b0 = *(const float4*)&sB[k][tx * 4];
      float a[8] = {a0.x, a0.y, a0.z, a0.w, a1.x, a1.y, a1.z, a1.w};
      float b[4] = {b0.x, b0.y, b0.z, b0.w};
#pragma unroll
      for (int ii = 0; ii < 8; ++ii)
#pragma unroll
        for (int j = 0; j < 4; ++j) acc2[ii][j] = fmaf(a[ii], b[j], acc2[ii][j]);
    }
  }
#pragma unroll
  for (int ii = 0; ii < 8; ++ii) {
    float4 v = {acc2[ii][0], acc2[ii][1], acc2[ii][2], acc2[ii][3]};
    *(float4*)(Xbs + (size_t)(rb + ty * 8 + ii) * NCOUT + cb + tx * 4) = v;
  }
  __threadfence();
  __syncthreads();
  if (tid == 0)
    __hip_atomic_store(&flags[fbb + r], 1, __ATOMIC_RELEASE,
                       __HIP_MEMORY_SCOPE_AGENT);
  float wp = 0.f;
#pragma unroll
  for (int ii = 0; ii < 8; ++ii)
#pragma unroll
    for (int j = 0; j < 4; ++j) wp += acc2[ii][j] * acc2[ii][j];
#pragma unroll
  for (int m2 = 32; m2 >= 1; m2 >>= 1) wp += __shfl_xor(wp, m2, 64);
  __syncthreads();
  if (lane == 0) red[wave] = wp;
  __syncthreads();
  if (tid == 0) atomicAdd(pp + 4 + s, red[0] + red[1] + red[2] + red[3]);
  for (int kk = 0; kk < 4; ++kk) {
    __syncthreads();
    if ((ty >> 2) == kk) {
      int kloc = ty * 8 - kk * 32;
#pragma unroll
      for (int ii = 0; ii < 8; ++ii) {
        float4 v = {acc2[ii][0], acc2[ii][1], acc2[ii][2], acc2[ii][3]};
        *(float4*)&sB[kloc + ii][tx * 4] = v;
      }
    }
    __syncthreads();
    {
      int c = tid >> 2, d8 = (tid & 3) * 8;
      float t0 = sB[d8 + 0][c], t1 = sB[d8 + 1][c], t2 = sB[d8 + 2][c], t3 = sB[d8 + 3][c];
      float t4 = sB[d8 + 4][c], t5 = sB[d8 + 5][c], t6 = sB[d8 + 6][c], t7 = sB[d8 + 7][c];
      float* dst = Wm + ((size_t)(s * NCOUT) + cb + c) * ND + rb + kk * 32 + d8;
      float4 w0 = {t0, t1, t2, t3}, w1 = {t4, t5, t6, t7};
      *(float4*)dst = w0;
      *(float4*)(dst + 4) = w1;
    }
  }
}

__global__ __launch_bounds__(256) void k_finalize(const float* __restrict__ logd,
                                                  const float* __restrict__ pp,
                                                  float* __restrict__ out) {
  int s = blockIdx.x, tid = threadIdx.x;
  __shared__ float r0[256];
  float l = 0.f;
  for (int i = tid; i < ND; i += 256) l += logd[s * ND + i];
  r0[tid] = l;
  __syncthreads();
  for (int off = 128; off; off >>= 1) {
    if (tid < off) r0[tid] += r0[tid + off];
    __syncthreads();
  }
  if (tid == 0) {
    float logdet = 2.0f * r0[0];
    out[s] = 0.5f * (pp[s] - pp[4 + s]) - 128.0f * logdet;
  }
}

// ---------------- launcher ----------------
extern "C" void kernel_launch(void* const* d_in, const int* in_sizes, int n_in,
                              void* d_out, int out_size, void* d_ws, size_t ws_size,
                              hipStream_t stream) {
  const float* X = (const float*)d_in[0];
  const float* u = (const float*)d_in[1];
  const float* lp = (const float*)d_in[2];
  const float* Z = (const float*)d_in[3];
  float* out = (float*)d_out;

  float* ws = (float*)d_ws;
  float* sp    = ws;                                    // 64
  float* logd  = sp + 64;                               // 4608
  float* pp    = logd + (size_t)NS * ND;                // 64
  int*   flags = (int*)(pp + 64);                       // 2048 ints
  float* iD    = (float*)(flags + 2048);                // 4*9*16384
  float* Xf    = iD + (size_t)NS * 9 * 16384;           // 4*1152*256
  float* Xb    = Xf + (size_t)NS * ND * NCOUT;          // 4*1152*256
  float* prec  = Xb + (size_t)NS * ND * NCOUT;          // 4*1152*1152
  float* prec2 = prec + (size_t)NS * D2;                // 4*1152*1152
  float* XLY   = prec2 + (size_t)NS * D2;               // 4*1152*256
  float* XLY2  = XLY + (size_t)NS * ND * NCOUT;         // 4*1152*256
  unsigned short* Phi = (unsigned short*)(XLY2 + (size_t)NS * ND * NCOUT);
  unsigned short* Plo = Phi + (size_t)NS * ND * NK;
  unsigned short* Yhi = Plo + (size_t)NS * ND * NK;
  unsigned short* Ylo = Yhi + (size_t)NCOUT * NK;

  hipMemsetAsync(flags, 0, 2048 * sizeof(int), stream);
  k_sqrtp<<<1, 64, 0, stream>>>(lp, sp, pp);
  k_patches<<<dim3(ND, NS), 128, 0, stream>>>(X, sp, Phi, Plo);
  k_ytt<<<NCOUT, 128, 0, stream>>>(u, sp, Yhi, Ylo);
  k_gemm_mfma<<<dim3(11, 9, NS * 2), 256, 0, stream>>>(Phi, Plo, Yhi, Ylo, prec,
                                                       prec2, XLY, XLY2);
  k_chol128<<<dim3(45, NS), 256, 0, stream>>>(prec, prec2, iD, logd, flags);
  k_solve2<<<dim3(9, 4, NS), 256, 0, stream>>>(prec, iD, XLY, XLY2, Z, Xf, Xb,
                                               out, pp, flags);
  k_finalize<<<NS, 256, 0, stream>>>(logd, pp, out + (size_t)NS * NCOUT * ND);
}

// Round 9
// 2213.924 us; speedup vs baseline: 1.2299x; 1.1589x over previous
//
#include <hip/hip_runtime.h>
#include <math.h>

#define NS 4
#define NB 32
#define CIN 128
#define NCOUT 256
#define HWN 256
#define ND 1152
#define NK 8192   // NB*HWN
static const size_t D2 = (size_t)ND * ND;

typedef __attribute__((ext_vector_type(8))) short bf16x8;
typedef __attribute__((ext_vector_type(4))) float f32x4;

static __device__ inline unsigned short f2bf(float x) {
  unsigned int u = __float_as_uint(x);
  unsigned int r = (u + 0x7fffu + ((u >> 16) & 1u)) >> 16;
  return (unsigned short)r;
}
static __device__ inline float bf2f(unsigned short h) {
  return __uint_as_float(((unsigned int)h) << 16);
}

// ---------------- small prep kernels ----------------

__global__ void k_sqrtp(const float* __restrict__ lp, float* __restrict__ sp,
                        float* __restrict__ pp) {
  int b = threadIdx.x;
  if (b < NB) sp[b] = expf(0.5f * lp[b]);
  if (b < 8) pp[b] = 0.f;
}

__global__ __launch_bounds__(128) void k_patches(const float* __restrict__ X,
                                                 const float* __restrict__ sp,
                                                 unsigned short* __restrict__ Phi,
                                                 unsigned short* __restrict__ Plo) {
  int d = blockIdx.x, s = blockIdx.y, t = threadIdx.x;
  int c = d / 9, r = d % 9, ky = r / 3, kx = r % 3;
  int p0 = t * 2;
  int yy = (p0 >> 4) + ky - 1;
  int xx0 = (p0 & 15) + kx - 1;
  bool oky = (yy >= 0 && yy < 16);
  bool ok0 = oky && (xx0 >= 0) && (xx0 < 16);
  bool ok1 = oky && (xx0 + 1 >= 0) && (xx0 + 1 < 16);
  int xo = yy * 16 + xx0;
  size_t base = ((size_t)s * ND + d) * NK + p0;
  for (int b = 0; b < NB; ++b) {
    float sb = sp[b];
    const float* xb = X + ((size_t)(s * NB + b) * CIN + c) * HWN;
    float v0 = ok0 ? xb[xo] * sb : 0.f;
    float v1 = ok1 ? xb[xo + 1] * sb : 0.f;
    unsigned short h0 = f2bf(v0), h1 = f2bf(v1);
    unsigned short l0 = f2bf(v0 - bf2f(h0)), l1 = f2bf(v1 - bf2f(h1));
    size_t idx = base + (size_t)b * HWN;
    *(unsigned int*)(Phi + idx) = (unsigned int)h0 | ((unsigned int)h1 << 16);
    *(unsigned int*)(Plo + idx) = (unsigned int)l0 | ((unsigned int)l1 << 16);
  }
}

__global__ __launch_bounds__(128) void k_ytt(const float* __restrict__ u,
                                             const float* __restrict__ sp,
                                             unsigned short* __restrict__ Yhi,
                                             unsigned short* __restrict__ Ylo) {
  int c = blockIdx.x, t = threadIdx.x;
  int p0 = t * 2;
  for (int b = 0; b < NB; ++b) {
    float sb = sp[b];
    const float* ub = u + ((size_t)b * NCOUT + c) * HWN + p0;
    float v0 = ub[0] * sb, v1 = ub[1] * sb;
    unsigned short h0 = f2bf(v0), h1 = f2bf(v1);
    unsigned short l0 = f2bf(v0 - bf2f(h0)), l1 = f2bf(v1 - bf2f(h1));
    size_t idx = (size_t)c * NK + (size_t)b * HWN + p0;
    *(unsigned int*)(Yhi + idx) = (unsigned int)h0 | ((unsigned int)h1 << 16);
    *(unsigned int*)(Ylo + idx) = (unsigned int)l0 | ((unsigned int)l1 << 16);
  }
}

// ---------------- bf16x3 MFMA XLX/XLY, K-split by 2 (partial sums) ----------------
__global__ __launch_bounds__(256) void k_gemm_mfma(
    const unsigned short* __restrict__ Phi, const unsigned short* __restrict__ Plo,
    const unsigned short* __restrict__ Yhi, const unsigned short* __restrict__ Ylo,
    float* __restrict__ prec, float* __restrict__ prec2,
    float* __restrict__ XLY, float* __restrict__ XLY2) {
  int jt = blockIdx.x, it = blockIdx.y;
  int s = blockIdx.z >> 1, kp = blockIdx.z & 1;
  bool isX = (jt <= it);
  if (!isX && jt < 9) return;
  int i0 = it * 128;
  int j0;
  const unsigned short *Bh, *Bl;
  if (isX) {
    j0 = jt * 128;
    Bh = Phi + ((size_t)s * ND + j0) * NK;
    Bl = Plo + ((size_t)s * ND + j0) * NK;
  } else {
    j0 = (jt - 9) * 128;
    Bh = Yhi + (size_t)j0 * NK;
    Bl = Ylo + (size_t)j0 * NK;
  }
  const unsigned short* Ah = Phi + ((size_t)s * ND + i0) * NK;
  const unsigned short* Al = Plo + ((size_t)s * ND + i0) * NK;

  __shared__ unsigned short sAh[4096], sAl[4096], sBh[4096], sBl[4096];
  int tid = threadIdx.x, wave = tid >> 6, lane = tid & 63;
  int wr = wave >> 1, wc = wave & 1;

  f32x4 zero = {0.f, 0.f, 0.f, 0.f};
  f32x4 acc[4][4];
#pragma unroll
  for (int m = 0; m < 4; ++m)
#pragma unroll
    for (int n = 0; n < 4; ++n) acc[m][n] = zero;

  const unsigned short* srcs[4] = {Ah, Al, Bh, Bl};
  unsigned short* dsts[4] = {sAh, sAl, sBh, sBl};
  int r0l = lane >> 2;
  int ke = (lane & 3) * 8;
  int arow0 = wr * 64 + (lane & 15);
  int brow0 = wc * 64 + (lane & 15);
  int koff = (lane >> 4) * 8;

  int kbeg = kp * (NK / 2), kend = kbeg + NK / 2;
  for (int k0 = kbeg; k0 < kend; k0 += 32) {
    __syncthreads();
#pragma unroll
    for (int f = 0; f < 4; ++f) {
#pragma unroll
      for (int cc = 0; cc < 2; ++cc) {
        int c = wave * 2 + cc;
        const unsigned short* g = srcs[f] + (size_t)(c * 16 + r0l) * NK + k0 + ke;
        unsigned short* l = dsts[f] + c * 512;
        __builtin_amdgcn_global_load_lds(
            (const __attribute__((address_space(1))) void*)g,
            (__attribute__((address_space(3))) void*)l, 16, 0, 0);
      }
    }
    __syncthreads();
    bf16x8 ah[4], al[4], bh[4], bl[4];
#pragma unroll
    for (int m = 0; m < 4; ++m) {
      int off = (arow0 + m * 16) * 32 + koff;
      ah[m] = *(const bf16x8*)&sAh[off];
      al[m] = *(const bf16x8*)&sAl[off];
    }
#pragma unroll
    for (int n = 0; n < 4; ++n) {
      int off = (brow0 + n * 16) * 32 + koff;
      bh[n] = *(const bf16x8*)&sBh[off];
      bl[n] = *(const bf16x8*)&sBl[off];
    }
#pragma unroll
    for (int m = 0; m < 4; ++m)
#pragma unroll
      for (int n = 0; n < 4; ++n) {
        acc[m][n] = __builtin_amdgcn_mfma_f32_16x16x32_bf16(ah[m], bh[n], acc[m][n], 0, 0, 0);
        acc[m][n] = __builtin_amdgcn_mfma_f32_16x16x32_bf16(ah[m], bl[n], acc[m][n], 0, 0, 0);
        acc[m][n] = __builtin_amdgcn_mfma_f32_16x16x32_bf16(al[m], bh[n], acc[m][n], 0, 0, 0);
      }
  }

  if (isX) {
    float* base = (kp ? prec2 : prec) + (size_t)s * D2;
#pragma unroll
    for (int m = 0; m < 4; ++m) {
      int row = i0 + wr * 64 + m * 16 + (lane >> 4) * 4;
#pragma unroll
      for (int n = 0; n < 4; ++n) {
        int col = j0 + wc * 64 + n * 16 + (lane & 15);
        float* cp = base + (size_t)row * ND + col;
#pragma unroll
        for (int r = 0; r < 4; ++r) cp[(size_t)r * ND] = acc[m][n][r];
      }
    }
  } else {
    float* base = (kp ? XLY2 : XLY) + (size_t)s * ND * NCOUT;
#pragma unroll
    for (int m = 0; m < 4; ++m) {
      int row = i0 + wr * 64 + m * 16 + (lane >> 4) * 4;
#pragma unroll
      for (int n = 0; n < 4; ++n) {
        int col = j0 + wc * 64 + n * 16 + (lane & 15);
        float* cp = base + (size_t)row * NCOUT + col;
#pragma unroll
        for (int r = 0; r < 4; ++r) cp[(size_t)r * NCOUT] = acc[m][n][r];
      }
    }
  }
}

// ---------------- merge K-split partials into prec (+ prior I), lower tiles ----------------
__global__ __launch_bounds__(256) void k_sumprec(float* __restrict__ prec,
                                                 const float* __restrict__ prec2) {
  int t = blockIdx.x, s = blockIdx.y;
  int bi = 0;
  while ((bi + 1) * (bi + 2) / 2 <= t) ++bi;
  int bj = t - bi * (bi + 1) / 2;
  int ib = bi * 64, jb = bj * 64;
  float* Ls = prec + (size_t)s * D2;
  const float* Ps = prec2 + (size_t)s * D2;
  int tid = threadIdx.x;
  int r2 = tid >> 2, c4 = (tid & 3) * 16;
  int row = ib + r2;
#pragma unroll
  for (int m = 0; m < 4; ++m) {
    size_t idx = (size_t)row * ND + jb + c4 + m * 4;
    float4 v = *(const float4*)(Ls + idx);
    float4 p = *(const float4*)(Ps + idx);
    v.x += p.x; v.y += p.y; v.z += p.z; v.w += p.w;
    if (bi == bj) {
      int colb = c4 + m * 4;
      if (r2 == colb + 0) v.x += 1.f;
      if (r2 == colb + 1) v.y += 1.f;
      if (r2 == colb + 2) v.z += 1.f;
      if (r2 == colb + 3) v.w += 1.f;
    }
    *(float4*)(Ls + idx) = v;
  }
}

// ---------------- blocked Cholesky, NB=64, multi-launch (proven R5 path) ----------------
__global__ __launch_bounds__(64) void k_chol_panel(float* __restrict__ L,
                                                   float* __restrict__ invd,
                                                   float* __restrict__ logd, int q) {
  const int s = blockIdx.x;
  const int strip = blockIdx.y;
  const int lane = threadIdx.x;
  const int j0 = q * 64;
  float* Ls = L + (size_t)s * D2;
  __shared__ float tile[64][65];
  for (int r = 0; r < 64; ++r) tile[r][lane] = Ls[(size_t)(j0 + r) * ND + j0 + lane];
  __syncthreads();
  float a[64];
#pragma unroll
  for (int t = 0; t < 64; ++t) a[t] = tile[lane][t];
  float diagv = 1.f;
#pragma unroll
  for (int j = 0; j < 64; ++j) {
    float dj = __shfl(a[j], j, 64);
    float rinv = 1.0f / sqrtf(dj);
    a[j] *= rinv;
    if (lane == j) diagv = a[j];
#pragma unroll
    for (int t = j + 1; t < 64; ++t) {
      float ltj = __shfl(a[j], t, 64);
      a[t] = fmaf(-a[j], ltj, a[t]);
    }
  }
  if (strip == 0) {
    __syncthreads();
#pragma unroll
    for (int t = 0; t < 64; ++t) tile[lane][t] = a[t];
    __syncthreads();
    for (int r = 0; r < 64; ++r) Ls[(size_t)(j0 + r) * ND + j0 + lane] = tile[r][lane];
    invd[s * ND + j0 + lane] = 1.0f / diagv;
    logd[s * ND + j0 + lane] = logf(diagv);
  } else {
    const int r0 = j0 + 64 * strip;
    __syncthreads();
    for (int r = 0; r < 64; ++r) tile[r][lane] = Ls[(size_t)(r0 + r) * ND + j0 + lane];
    __syncthreads();
    float b[64];
#pragma unroll
    for (int t = 0; t < 64; ++t) b[t] = tile[lane][t];
#pragma unroll
    for (int j = 0; j < 64; ++j) {
      float dj = __shfl(a[j], j, 64);
      b[j] *= (1.0f / dj);
#pragma unroll
      for (int t = j + 1; t < 64; ++t) {
        float ltj = __shfl(a[j], t, 64);
        b[t] = fmaf(-b[j], ltj, b[t]);
      }
    }
    __syncthreads();
#pragma unroll
    for (int t = 0; t < 64; ++t) tile[lane][t] = b[t];
    __syncthreads();
    for (int r = 0; r < 64; ++r) Ls[(size_t)(r0 + r) * ND + j0 + lane] = tile[r][lane];
  }
}

__global__ __launch_bounds__(256) void k_chol_update(float* __restrict__ L, int q) {
  int ti = blockIdx.x, tj = blockIdx.y, s = blockIdx.z;
  if (ti < tj) return;
  int j0 = q * 64;
  int r0 = j0 + 64 + ti * 64;
  int c0 = j0 + 64 + tj * 64;
  float* Ls = L + (size_t)s * D2;
  __shared__ float At[64][64];
  __shared__ float Bt[64][64];
  int tid = threadIdx.x;
  {
    int a = tid >> 2, km = (tid & 3) * 4;
#pragma unroll
    for (int m = 0; m < 4; ++m) {
      float4 v = *(const float4*)(Ls + (size_t)(r0 + a) * ND + j0 + km + m * 16);
      At[km + m * 16 + 0][a] = v.x;
      At[km + m * 16 + 1][a] = v.y;
      At[km + m * 16 + 2][a] = v.z;
      At[km + m * 16 + 3][a] = v.w;
      float4 w = *(const float4*)(Ls + (size_t)(c0 + a) * ND + j0 + km + m * 16);
      Bt[km + m * 16 + 0][a] = w.x;
      Bt[km + m * 16 + 1][a] = w.y;
      Bt[km + m * 16 + 2][a] = w.z;
      Bt[km + m * 16 + 3][a] = w.w;
    }
  }
  __syncthreads();
  int tx = tid & 15, ty = tid >> 4;
  float acc[4][4] = {};
#pragma unroll
  for (int k = 0; k < 64; ++k) {
    float4 a4 = *(const float4*)&At[k][ty * 4];
    float4 b4 = *(const float4*)&Bt[k][tx * 4];
    float ar[4] = {a4.x, a4.y, a4.z, a4.w};
    float br[4] = {b4.x, b4.y, b4.z, b4.w};
#pragma unroll
    for (int r = 0; r < 4; ++r)
#pragma unroll
      for (int e = 0; e < 4; ++e) acc[r][e] = fmaf(ar[r], br[e], acc[r][e]);
  }
#pragma unroll
  for (int r = 0; r < 4; ++r) {
    float* cp = Ls + (size_t)(r0 + ty * 4 + r) * ND + c0 + tx * 4;
    float4 c = *(const float4*)cp;
    c.x -= acc[r][0]; c.y -= acc[r][1]; c.z -= acc[r][2]; c.w -= acc[r][3];
    *(float4*)cp = c;
  }
}

// ---------------- invert 128x128 diag blocks (wave-parallel, R5-proven) ----------------
__global__ __launch_bounds__(256) void k_invd128(const float* __restrict__ L,
                                                 float* __restrict__ iD) {
  int q = blockIdx.x, s = blockIdx.y;
  int tid = threadIdx.x, lane = tid & 63, w = tid >> 6;
  const float* Ls = L + (size_t)s * D2;
  float* out = iD + ((size_t)(s * 9 + q)) * 16384;
  int b0 = q * 128;
  __shared__ float inv0[64][65];
  __shared__ float invCt[64][65];
  __shared__ float Bt[64][65];
  __shared__ float Tl[64][65];

  if (w < 2) {
    const float* base = Ls + (size_t)(b0 + w * 64) * ND + b0 + w * 64;
    float lcol[64], x[64];
#pragma unroll
    for (int i = 0; i < 64; ++i) {
      lcol[i] = base[(size_t)i * ND + lane];
      x[i] = (i == lane) ? 1.f : 0.f;
    }
#pragma unroll
    for (int j = 0; j < 64; ++j) {
      float ljj = __shfl(lcol[j], j, 64);
      float xj = x[j] / ljj;
      x[j] = xj;
#pragma unroll
      for (int i = j + 1; i < 64; ++i) {
        float lij = __shfl(lcol[i], j, 64);
        x[i] = fmaf(-lij, xj, x[i]);
      }
    }
    if (w == 0) {
#pragma unroll
      for (int i = 0; i < 64; ++i) inv0[i][lane] = x[i];
    } else {
#pragma unroll
      for (int i = 0; i < 64; ++i) invCt[lane][i] = x[i];
    }
  } else {
    int t = tid - 128;
    int i = t & 63, kh = (t >> 6) * 32;
    const float* src = Ls + (size_t)(b0 + 64 + i) * ND + b0 + kh;
#pragma unroll
    for (int m = 0; m < 8; ++m) {
      float4 v = *(const float4*)(src + m * 4);
      Bt[kh + m * 4 + 0][i] = v.x;
      Bt[kh + m * 4 + 1][i] = v.y;
      Bt[kh + m * 4 + 2][i] = v.z;
      Bt[kh + m * 4 + 3][i] = v.w;
    }
  }
  __syncthreads();

  int tx = tid & 15, ty = tid >> 4;
  float acc[4][4] = {};
#pragma unroll
  for (int k = 0; k < 64; ++k) {
    float a4[4], b4[4];
#pragma unroll
    for (int e = 0; e < 4; ++e) { a4[e] = Bt[k][ty * 4 + e]; b4[e] = inv0[k][tx * 4 + e]; }
#pragma unroll
    for (int r = 0; r < 4; ++r)
#pragma unroll
      for (int e = 0; e < 4; ++e) acc[r][e] = fmaf(a4[r], b4[e], acc[r][e]);
  }
#pragma unroll
  for (int r = 0; r < 4; ++r)
#pragma unroll
    for (int e = 0; e < 4; ++e) Tl[ty * 4 + r][tx * 4 + e] = acc[r][e];
  __syncthreads();
  float acc2[4][4] = {};
#pragma unroll
  for (int k = 0; k < 64; ++k) {
    float a4[4], b4[4];
#pragma unroll
    for (int e = 0; e < 4; ++e) { a4[e] = invCt[k][ty * 4 + e]; b4[e] = Tl[k][tx * 4 + e]; }
#pragma unroll
    for (int r = 0; r < 4; ++r)
#pragma unroll
      for (int e = 0; e < 4; ++e) acc2[r][e] = fmaf(a4[r], b4[e], acc2[r][e]);
  }
  {
    int rrow = tid >> 2, cc = (tid & 3) * 32;
    float* o = out + rrow * 128 + cc;
    if (cc < 64) {
#pragma unroll
      for (int m = 0; m < 8; ++m) {
        float4 v = {inv0[rrow][cc + m * 4 + 0], inv0[rrow][cc + m * 4 + 1],
                    inv0[rrow][cc + m * 4 + 2], inv0[rrow][cc + m * 4 + 3]};
        *(float4*)(o + m * 4) = v;
      }
    } else {
      float4 z = {0.f, 0.f, 0.f, 0.f};
#pragma unroll
      for (int m = 0; m < 8; ++m) *(float4*)(o + m * 4) = z;
    }
  }
#pragma unroll
  for (int r = 0; r < 4; ++r) {
    float4 v = {-acc2[r][0], -acc2[r][1], -acc2[r][2], -acc2[r][3]};
    *(float4*)(out + (size_t)(64 + ty * 4 + r) * 128 + tx * 4) = v;
  }
  {
    int i = tid >> 2, jc = (tid & 3) * 16;
#pragma unroll
    for (int m = 0; m < 4; ++m) {
      float4 v = {invCt[jc + m * 4 + 0][i], invCt[jc + m * 4 + 1][i],
                  invCt[jc + m * 4 + 2][i], invCt[jc + m * 4 + 3][i]};
      *(float4*)(out + (size_t)(64 + i) * 128 + 64 + jc + m * 4) = v;
    }
  }
}

// ---------------- merged persistent fwd+bwd solve (fused addz/writewm) ----------------
__global__ __launch_bounds__(256) void k_solve2(
    const float* __restrict__ L, const float* __restrict__ iD,
    const float* __restrict__ B1, const float* __restrict__ B2,
    const float* __restrict__ Z, float* __restrict__ Xf, float* __restrict__ Xb,
    float* __restrict__ Wm, float* __restrict__ pp, int* __restrict__ flags) {
  int r = blockIdx.x, ct = blockIdx.y, s = blockIdx.z;
  int rb = r * 128, cb = ct * 64;
  const float* Ls = L + (size_t)s * D2;
  const float* Dq = iD + ((size_t)(s * 9 + r)) * 16384;
  float* Xfs = Xf + (size_t)s * ND * NCOUT;
  float* Xbs = Xb + (size_t)s * ND * NCOUT;
  int fbf = 1296 + (s * 4 + ct) * 9;
  int fbb = 1440 + (s * 4 + ct) * 9;

  __shared__ float sA[32][132];
  __shared__ float sB[32][68];
  __shared__ float red[8];
  int tid = threadIdx.x, tx = tid & 15, ty = tid >> 4;
  int wave = tid >> 6, lane = tid & 63;

  // ======== forward ========
  float acc[8][4];
#pragma unroll
  for (int ii = 0; ii < 8; ++ii) {
    size_t idx = (size_t)s * ND * NCOUT + (size_t)(rb + ty * 8 + ii) * NCOUT + cb + tx * 4;
    float4 v = *(const float4*)(B1 + idx);
    float4 v2 = *(const float4*)(B2 + idx);
    acc[ii][0] = v.x + v2.x; acc[ii][1] = v.y + v2.y;
    acc[ii][2] = v.z + v2.z; acc[ii][3] = v.w + v2.w;
  }
  for (int q = 0; q < r; ++q) {
    if (tid == 0) {
      while (__hip_atomic_load(&flags[fbf + q], __ATOMIC_RELAXED,
                               __HIP_MEMORY_SCOPE_AGENT) == 0)
        __builtin_amdgcn_s_sleep(2);
      (void)__hip_atomic_load(&flags[fbf + q], __ATOMIC_ACQUIRE,
                              __HIP_MEMORY_SCOPE_AGENT);
    }
    __syncthreads();
    int qb = q * 128;
    for (int kk = 0; kk < 4; ++kk) {
      __syncthreads();
      {
        int i = tid >> 1, kb = (tid & 1) * 16;
        const float* src = Ls + (size_t)(rb + i) * ND + qb + kk * 32 + kb;
#pragma unroll
        for (int m = 0; m < 4; ++m) {
          float4 v = *(const float4*)(src + m * 4);
          sA[kb + m * 4 + 0][i] = v.x;
          sA[kb + m * 4 + 1][i] = v.y;
          sA[kb + m * 4 + 2][i] = v.z;
          sA[kb + m * 4 + 3][i] = v.w;
        }
      }
      {
        int k = tid >> 3, jb2 = (tid & 7) * 8;
        const float* src = Xfs + (size_t)(qb + kk * 32 + k) * NCOUT + cb + jb2;
        float4 v0 = *(const float4*)src;
        float4 v1 = *(const float4*)(src + 4);
        *(float4*)&sB[k][jb2] = v0;
        *(float4*)&sB[k][jb2 + 4] = v1;
      }
      __syncthreads();
#pragma unroll
      for (int k = 0; k < 32; ++k) {
        float4 a0 = *(const float4*)&sA[k][ty * 8];
        float4 a1 = *(const float4*)&sA[k][ty * 8 + 4];
        float4 b0 = *(const float4*)&sB[k][tx * 4];
        float a[8] = {a0.x, a0.y, a0.z, a0.w, a1.x, a1.y, a1.z, a1.w};
        float b[4] = {b0.x, b0.y, b0.z, b0.w};
#pragma unroll
        for (int ii = 0; ii < 8; ++ii)
#pragma unroll
          for (int j = 0; j < 4; ++j) acc[ii][j] = fmaf(-a[ii], b[j], acc[ii][j]);
      }
    }
  }
  float acc2[8][4] = {};
  for (int kk = 0; kk < 4; ++kk) {
    __syncthreads();
    if ((ty >> 2) == kk) {
      int kloc = ty * 8 - kk * 32;
#pragma unroll
      for (int ii = 0; ii < 8; ++ii) {
        float4 v = {acc[ii][0], acc[ii][1], acc[ii][2], acc[ii][3]};
        *(float4*)&sB[kloc + ii][tx * 4] = v;
      }
    }
    {
      int i = tid >> 1, kb = (tid & 1) * 16;
      const float* src = Dq + (size_t)i * 128 + kk * 32 + kb;
#pragma unroll
      for (int m = 0; m < 4; ++m) {
        float4 v = *(const float4*)(src + m * 4);
        sA[kb + m * 4 + 0][i] = v.x;
        sA[kb + m * 4 + 1][i] = v.y;
        sA[kb + m * 4 + 2][i] = v.z;
        sA[kb + m * 4 + 3][i] = v.w;
      }
    }
    __syncthreads();
#pragma unroll
    for (int k = 0; k < 32; ++k) {
      float4 a0 = *(const float4*)&sA[k][ty * 8];
      float4 a1 = *(const float4*)&sA[k][ty * 8 + 4];
      float4 b0 = *(const float4*)&sB[k][tx * 4];
      float a[8] = {a0.x, a0.y, a0.z, a0.w, a1.x, a1.y, a1.z, a1.w};
      float b[4] = {b0.x, b0.y, b0.z, b0.w};
#pragma unroll
      for (int ii = 0; ii < 8; ++ii)
#pragma unroll
        for (int j = 0; j < 4; ++j) acc2[ii][j] = fmaf(a[ii], b[j], acc2[ii][j]);
    }
  }
#pragma unroll
  for (int ii = 0; ii < 8; ++ii) {
    float4 v = {acc2[ii][0], acc2[ii][1], acc2[ii][2], acc2[ii][3]};
    *(float4*)(Xfs + (size_t)(rb + ty * 8 + ii) * NCOUT + cb + tx * 4) = v;
  }
  __threadfence();
  __syncthreads();
  if (tid == 0)
    __hip_atomic_store(&flags[fbf + r], 1, __ATOMIC_RELEASE,
                       __HIP_MEMORY_SCOPE_AGENT);

  // ======== backward (init from fwd result in registers) ========
#pragma unroll
  for (int ii = 0; ii < 8; ++ii)
#pragma unroll
    for (int j = 0; j < 4; ++j) acc[ii][j] = acc2[ii][j];

  float zp = 0.f;
  for (int kk = 0; kk < 4; ++kk) {
    __syncthreads();
    {
      int c = tid >> 2, d8 = (tid & 3) * 8;
      const float* src = Z + ((size_t)(s * NCOUT) + cb + c) * ND + rb + kk * 32 + d8;
      float4 v0 = *(const float4*)src;
      float4 v1 = *(const float4*)(src + 4);
      sA[d8 + 0][c] = v0.x; sA[d8 + 1][c] = v0.y; sA[d8 + 2][c] = v0.z; sA[d8 + 3][c] = v0.w;
      sA[d8 + 4][c] = v1.x; sA[d8 + 5][c] = v1.y; sA[d8 + 6][c] = v1.z; sA[d8 + 7][c] = v1.w;
      zp += v0.x * v0.x + v0.y * v0.y + v0.z * v0.z + v0.w * v0.w;
      zp += v1.x * v1.x + v1.y * v1.y + v1.z * v1.z + v1.w * v1.w;
    }
    __syncthreads();
    if ((ty >> 2) == kk) {
      int kloc = ty * 8 - kk * 32;
#pragma unroll
      for (int ii = 0; ii < 8; ++ii) {
        float4 v = *(const float4*)&sA[kloc + ii][tx * 4];
        acc[ii][0] += v.x; acc[ii][1] += v.y; acc[ii][2] += v.z; acc[ii][3] += v.w;
      }
    }
  }
#pragma unroll
  for (int m2 = 32; m2 >= 1; m2 >>= 1) zp += __shfl_xor(zp, m2, 64);
  if (lane == 0) red[wave] = zp;
  __syncthreads();
  if (tid == 0) atomicAdd(pp + s, red[0] + red[1] + red[2] + red[3]);

  for (int q = 8; q > r; --q) {
    if (tid == 0) {
      while (__hip_atomic_load(&flags[fbb + q], __ATOMIC_RELAXED,
                               __HIP_MEMORY_SCOPE_AGENT) == 0)
        __builtin_amdgcn_s_sleep(2);
      (void)__hip_atomic_load(&flags[fbb + q], __ATOMIC_ACQUIRE,
                              __HIP_MEMORY_SCOPE_AGENT);
    }
    __syncthreads();
    int qb = q * 128;
    for (int kk = 0; kk < 4; ++kk) {
      __syncthreads();
      {
        int k = tid >> 3, ib2 = (tid & 7) * 16;
        const float* src = Ls + (size_t)(qb + kk * 32 + k) * ND + rb + ib2;
#pragma unroll
        for (int m = 0; m < 4; ++m)
          *(float4*)&sA[k][ib2 + m * 4] = *(const float4*)(src + m * 4);
      }
      {
        int k = tid >> 3, jb2 = (tid & 7) * 8;
        const float* src = Xbs + (size_t)(qb + kk * 32 + k) * NCOUT + cb + jb2;
        float4 v0 = *(const float4*)src;
        float4 v1 = *(const float4*)(src + 4);
        *(float4*)&sB[k][jb2] = v0;
        *(float4*)&sB[k][jb2 + 4] = v1;
      }
      __syncthreads();
#pragma unroll
      for (int k = 0; k < 32; ++k) {
        float4 a0 = *(const float4*)&sA[k][ty * 8];
        float4 a1 = *(const float4*)&sA[k][ty * 8 + 4];
        float4 b0 = *(const float4*)&sB[k][tx * 4];
        float a[8] = {a0.x, a0.y, a0.z, a0.w, a1.x, a1.y, a1.z, a1.w};
        float b[4] = {b0.x, b0.y, b0.z, b0.w};
#pragma unroll
        for (int ii = 0; ii < 8; ++ii)
#pragma unroll
          for (int j = 0; j < 4; ++j) acc[ii][j] = fmaf(-a[ii], b[j], acc[ii][j]);
      }
    }
  }
#pragma unroll
  for (int ii = 0; ii < 8; ++ii)
#pragma unroll
    for (int j = 0; j < 4; ++j) acc2[ii][j] = 0.f;
  for (int kk = 0; kk < 4; ++kk) {
    __syncthreads();
    if ((ty >> 2) == kk) {
      int kloc = ty * 8 - kk * 32;
#pragma unroll
      for (int ii = 0; ii < 8; ++ii) {
        float4 v = {acc[ii][0], acc[ii][1], acc[ii][2], acc[ii][3]};
        *(float4*)&sB[kloc + ii][tx * 4] = v;
      }
    }
    {
      int k = tid >> 3, ib2 = (tid & 7) * 16;
      const float* src = Dq + (size_t)(kk * 32 + k) * 128 + ib2;
#pragma unroll
      for (int m = 0; m < 4; ++m)
        *(float4*)&sA[k][ib2 + m * 4] = *(const float4*)(src + m * 4);
    }
    __syncthreads();
#pragma unroll
    for (int k = 0; k < 32; ++k) {
      float4 a0 = *(const float4*)&sA[k][ty * 8];
      float4 a1 = *(const float4*)&sA[k][ty * 8 + 4];
      float4 b0 = *(const float4*)&sB[k][tx * 4];
      float a[8] = {a0.x, a0.y, a0.z, a0.w, a1.x, a1.y, a1.z, a1.w};
      float b[4] = {b0.x, b0.y, b0.z, b0.w};
#pragma unroll
      for (int ii = 0; ii < 8; ++ii)
#pragma unroll
        for (int j = 0; j < 4; ++j) acc2[ii][j] = fmaf(a[ii], b[j], acc2[ii][j]);
    }
  }
#pragma unroll
  for (int ii = 0; ii < 8; ++ii) {
    float4 v = {acc2[ii][0], acc2[ii][1], acc2[ii][2], acc2[ii][3]};
    *(float4*)(Xbs + (size_t)(rb + ty * 8 + ii) * NCOUT + cb + tx * 4) = v;
  }
  __threadfence();
  __syncthreads();
  if (tid == 0)
    __hip_atomic_store(&flags[fbb + r], 1, __ATOMIC_RELEASE,
                       __HIP_MEMORY_SCOPE_AGENT);
  float wp = 0.f;
#pragma unroll
  for (int ii = 0; ii < 8; ++ii)
#pragma unroll
    for (int j = 0; j < 4; ++j) wp += acc2[ii][j] * acc2[ii][j];
#pragma unroll
  for (int m2 = 32; m2 >= 1; m2 >>= 1) wp += __shfl_xor(wp, m2, 64);
  __syncthreads();
  if (lane == 0) red[wave] = wp;
  __syncthreads();
  if (tid == 0) atomicAdd(pp + 4 + s, red[0] + red[1] + red[2] + red[3]);
  for (int kk = 0; kk < 4; ++kk) {
    __syncthreads();
    if ((ty >> 2) == kk) {
      int kloc = ty * 8 - kk * 32;
#pragma unroll
      for (int ii = 0; ii < 8; ++ii) {
        float4 v = {acc2[ii][0], acc2[ii][1], acc2[ii][2], acc2[ii][3]};
        *(float4*)&sB[kloc + ii][tx * 4] = v;
      }
    }
    __syncthreads();
    {
      int c = tid >> 2, d8 = (tid & 3) * 8;
      float t0 = sB[d8 + 0][c], t1 = sB[d8 + 1][c], t2 = sB[d8 + 2][c], t3 = sB[d8 + 3][c];
      float t4 = sB[d8 + 4][c], t5 = sB[d8 + 5][c], t6 = sB[d8 + 6][c], t7 = sB[d8 + 7][c];
      float* dst = Wm + ((size_t)(s * NCOUT) + cb + c) * ND + rb + kk * 32 + d8;
      float4 w0 = {t0, t1, t2, t3}, w1 = {t4, t5, t6, t7};
      *(float4*)dst = w0;
      *(float4*)(dst + 4) = w1;
    }
  }
}

__global__ __launch_bounds__(256) void k_finalize(const float* __restrict__ logd,
                                                  const float* __restrict__ pp,
                                                  float* __restrict__ out) {
  int s = blockIdx.x, tid = threadIdx.x;
  __shared__ float r0[256];
  float l = 0.f;
  for (int i = tid; i < ND; i += 256) l += logd[s * ND + i];
  r0[tid] = l;
  __syncthreads();
  for (int off = 128; off; off >>= 1) {
    if (tid < off) r0[tid] += r0[tid + off];
    __syncthreads();
  }
  if (tid == 0) {
    float logdet = 2.0f * r0[0];
    out[s] = 0.5f * (pp[s] - pp[4 + s]) - 128.0f * logdet;
  }
}

// ---------------- launcher ----------------
extern "C" void kernel_launch(void* const* d_in, const int* in_sizes, int n_in,
                              void* d_out, int out_size, void* d_ws, size_t ws_size,
                              hipStream_t stream) {
  const float* X = (const float*)d_in[0];
  const float* u = (const float*)d_in[1];
  const float* lp = (const float*)d_in[2];
  const float* Z = (const float*)d_in[3];
  float* out = (float*)d_out;

  float* ws = (float*)d_ws;
  float* sp    = ws;                                    // 64
  float* invd  = sp + 64;                               // 4608
  float* logd  = invd + (size_t)NS * ND;                // 4608
  float* pp    = logd + (size_t)NS * ND;                // 64
  int*   flags = (int*)(pp + 64);                       // 2048 ints
  float* iD    = (float*)(flags + 2048);                // 4*9*16384
  float* Xf    = iD + (size_t)NS * 9 * 16384;           // 4*1152*256
  float* Xb    = Xf + (size_t)NS * ND * NCOUT;          // 4*1152*256
  float* prec  = Xb + (size_t)NS * ND * NCOUT;          // 4*1152*1152
  float* prec2 = prec + (size_t)NS * D2;                // 4*1152*1152
  float* XLY   = prec2 + (size_t)NS * D2;               // 4*1152*256
  float* XLY2  = XLY + (size_t)NS * ND * NCOUT;         // 4*1152*256
  unsigned short* Phi = (unsigned short*)(XLY2 + (size_t)NS * ND * NCOUT);
  unsigned short* Plo = Phi + (size_t)NS * ND * NK;
  unsigned short* Yhi = Plo + (size_t)NS * ND * NK;
  unsigned short* Ylo = Yhi + (size_t)NCOUT * NK;

  hipMemsetAsync(flags, 0, 2048 * sizeof(int), stream);
  k_sqrtp<<<1, 64, 0, stream>>>(lp, sp, pp);
  k_patches<<<dim3(ND, NS), 128, 0, stream>>>(X, sp, Phi, Plo);
  k_ytt<<<NCOUT, 128, 0, stream>>>(u, sp, Yhi, Ylo);
  k_gemm_mfma<<<dim3(11, 9, NS * 2), 256, 0, stream>>>(Phi, Plo, Yhi, Ylo, prec,
                                                       prec2, XLY, XLY2);
  k_sumprec<<<dim3(171, NS), 256, 0, stream>>>(prec, prec2);
  for (int q = 0; q < 18; ++q) {
    k_chol_panel<<<dim3(NS, 18 - q), 64, 0, stream>>>(prec, invd, logd, q);
    if (q < 17) {
      int m = 17 - q;
      k_chol_update<<<dim3(m, m, NS), 256, 0, stream>>>(prec, q);
    }
  }
  k_invd128<<<dim3(9, NS), 256, 0, stream>>>(prec, iD);
  k_solve2<<<dim3(9, 4, NS), 256, 0, stream>>>(prec, iD, XLY, XLY2, Z, Xf, Xb,
                                               out, pp, flags);
  k_finalize<<<NS, 256, 0, stream>>>(logd, pp, out + (size_t)NS * NCOUT * ND);
}